// Round 2
// baseline (5797.949 us; speedup 1.0000x reference)
//
#include <hip/hip_runtime.h>
#include <hip/hip_bf16.h>
#include <math.h>

typedef unsigned short u16;
typedef unsigned int   u32;

__device__ __forceinline__ float2 bfp2(u32 p){
  return make_float2(__uint_as_float(p<<16), __uint_as_float(p & 0xffff0000u));
}
__device__ __forceinline__ u16 f2bf(float f){
  u32 u = __float_as_uint(f);
  u += 0x7fffu + ((u>>16)&1u);          // RNE, inputs are never NaN
  return (u16)(u>>16);
}
__device__ __forceinline__ u32 pack2(float a, float b){
  return (u32)f2bf(a) | ((u32)f2bf(b)<<16);
}
__device__ __forceinline__ float2 LDF2(const float* p){ return *(const float2*)p; }
__device__ __forceinline__ float gelu_f(float v){
  return 0.5f*v*(1.0f + erff(v*0.70710678118654752f));
}

#define LD_U32(p)   (*(const u32*)(p))
#define ST_U32(p,v) (*(u32*)(p) = (v))

constexpr float SCALE_Q = 0.17677669529663687f;  // 32^-0.5
constexpr float LN_EPS  = 1e-5f;

// =====================================================================
// K1: shifted-window attention + proj + LN1 + residual  -> x1 (f32, =d_out)
// one block per window (4096 blocks), 256 threads
// =====================================================================
__global__ __launch_bounds__(256, 2) void k_attn(
    const float* __restrict__ x, const float* __restrict__ mask,
    const int* __restrict__ relidx, const float* __restrict__ qkv_w,
    const float* __restrict__ qkv_b, const float* __restrict__ proj_w,
    const float* __restrict__ proj_b, const float* __restrict__ rpb,
    const float* __restrict__ n1g, const float* __restrict__ n1b,
    float* __restrict__ x1)
{
  __shared__ u16 xw[64*194];     // window tokens (bf16), row stride 194
  __shared__ u16 qkvh[64*98];    // per-head q|k|v (32 each), row stride 98
  __shared__ u32 region3[3200];  // 12800 B union: wtq[32][194] / (prb[64][66]+outh[64][34]) / (wtp[96][34]+outh)
  u16* const wtq  = (u16*)region3;           // [0,12416) B
  u16* const prb  = (u16*)region3;           // [0,8448) B
  u16* const outh = (u16*)region3 + 4224;    // [8448,12800) B
  u16* const wtp  = (u16*)region3;           // [0,6528) B

  const int tid = threadIdx.x;
  const int tr = tid >> 4, tc = tid & 15;    // 16 token-groups x 16 col-groups
  const int wi = blockIdx.x;
  const int b  = wi >> 10;
  const int wm = wi & 1023;
  const int wh = wm >> 5, ww = wm & 31;
  const size_t imgbase = (size_t)b * (256*256*192);

  // ---- gather shifted window (roll -4,-4), f32 -> bf16 ----
  for (int s = tid; s < 64*96; s += 256){
    int t = s / 96, c2 = s - t*96;
    int i = t >> 3, j = t & 7;
    int h0 = ((wh<<3) + i + 4) & 255;
    int w0 = ((ww<<3) + j + 4) & 255;
    float2 v = LDF2(x + imgbase + (size_t)(h0*256 + w0)*192 + c2*2);
    ST_U32(xw + t*194 + c2*2, pack2(v.x, v.y));
  }

  // proj accumulators: 4 tokens x 12 channels (c = oc*32 + tc*2 + {0,1})
  float pj[4][12];
  #pragma unroll
  for (int oc = 0; oc < 6; ++oc){
    float2 pb = LDF2(proj_b + oc*32 + tc*2);
    #pragma unroll
    for (int ii = 0; ii < 4; ++ii){ pj[ii][oc*2] = pb.x; pj[ii][oc*2+1] = pb.y; }
  }
  __syncthreads();

  for (int h = 0; h < 6; ++h){
    // ---- q,k,v: three 64x32 GEMMs ----
    #pragma unroll 1
    for (int s3 = 0; s3 < 3; ++s3){
      int rbase = s3*192 + h*32;
      for (int s = tid; s < 32*96; s += 256){
        int rr = s / 96, c2 = s - rr*96;
        float2 v = LDF2(qkv_w + (size_t)(rbase+rr)*192 + c2*2);
        ST_U32(wtq + rr*194 + c2*2, pack2(v.x, v.y));
      }
      __syncthreads();
      float2 bia = LDF2(qkv_b + rbase + tc*2);
      float acc0[4], acc1[4];
      #pragma unroll
      for (int ii = 0; ii < 4; ++ii){ acc0[ii] = bia.x; acc1[ii] = bia.y; }
      const u16* wr0 = wtq + (tc*2)*194;
      const u16* wr1 = wr0 + 194;
      const u16* xr  = xw + (tr*4)*194;
      #pragma unroll 4
      for (int k2 = 0; k2 < 96; ++k2){
        float2 w0 = bfp2(LD_U32(wr0 + k2*2));
        float2 w1 = bfp2(LD_U32(wr1 + k2*2));
        #pragma unroll
        for (int ii = 0; ii < 4; ++ii){
          float2 a = bfp2(LD_U32(xr + ii*194 + k2*2));
          acc0[ii] = fmaf(a.x, w0.x, acc0[ii]);
          acc0[ii] = fmaf(a.y, w0.y, acc0[ii]);
          acc1[ii] = fmaf(a.x, w1.x, acc1[ii]);
          acc1[ii] = fmaf(a.y, w1.y, acc1[ii]);
        }
      }
      float scl = (s3 == 0) ? SCALE_Q : 1.0f;
      #pragma unroll
      for (int ii = 0; ii < 4; ++ii)
        ST_U32(qkvh + (tr*4+ii)*98 + s3*32 + tc*2, pack2(acc0[ii]*scl, acc1[ii]*scl));
      __syncthreads();
    }

    // ---- logits (registers): rows 4tr.., cols 4tc.. ----
    float lg[4][4];
    #pragma unroll
    for (int ii = 0; ii < 4; ++ii)
      #pragma unroll
      for (int jj = 0; jj < 4; ++jj) lg[ii][jj] = 0.f;
    #pragma unroll 2
    for (int d2 = 0; d2 < 16; ++d2){
      float2 kv[4];
      #pragma unroll
      for (int jj = 0; jj < 4; ++jj)
        kv[jj] = bfp2(LD_U32(qkvh + (tc*4+jj)*98 + 32 + d2*2));
      #pragma unroll
      for (int ii = 0; ii < 4; ++ii){
        float2 qv = bfp2(LD_U32(qkvh + (tr*4+ii)*98 + d2*2));
        #pragma unroll
        for (int jj = 0; jj < 4; ++jj){
          lg[ii][jj] = fmaf(qv.x, kv[jj].x, lg[ii][jj]);
          lg[ii][jj] = fmaf(qv.y, kv[jj].y, lg[ii][jj]);
        }
      }
    }
    const size_t mbase = (size_t)wm * 4096;
    #pragma unroll
    for (int ii = 0; ii < 4; ++ii){
      int i = tr*4 + ii;
      #pragma unroll
      for (int jj = 0; jj < 4; ++jj){
        int j = tc*4 + jj;
        lg[ii][jj] += rpb[relidx[i*64 + j]*6 + h] + mask[mbase + i*64 + j];
      }
    }

    // ---- softmax across row (16-lane group reduce) ----
    float inv_[4];
    #pragma unroll
    for (int ii = 0; ii < 4; ++ii){
      float m0 = fmaxf(fmaxf(lg[ii][0], lg[ii][1]), fmaxf(lg[ii][2], lg[ii][3]));
      #pragma unroll
      for (int mk = 1; mk < 16; mk <<= 1) m0 = fmaxf(m0, __shfl_xor(m0, mk));
      float s = 0.f;
      #pragma unroll
      for (int jj = 0; jj < 4; ++jj){ lg[ii][jj] = __expf(lg[ii][jj] - m0); s += lg[ii][jj]; }
      #pragma unroll
      for (int mk = 1; mk < 16; mk <<= 1) s += __shfl_xor(s, mk);
      inv_[ii] = 1.0f / s;
    }
    #pragma unroll
    for (int ii = 0; ii < 4; ++ii){
      ST_U32(prb + (tr*4+ii)*66 + tc*4,     pack2(lg[ii][0]*inv_[ii], lg[ii][1]*inv_[ii]));
      ST_U32(prb + (tr*4+ii)*66 + tc*4 + 2, pack2(lg[ii][2]*inv_[ii], lg[ii][3]*inv_[ii]));
    }
    __syncthreads();

    // ---- PV: out[i][d], d = 2tc + {0,1} ----
    float ov0[4] = {0,0,0,0}, ov1[4] = {0,0,0,0};
    #pragma unroll 2
    for (int j2 = 0; j2 < 32; ++j2){
      float2 va = bfp2(LD_U32(qkvh + (j2*2  )*98 + 64 + tc*2));
      float2 vb = bfp2(LD_U32(qkvh + (j2*2+1)*98 + 64 + tc*2));
      #pragma unroll
      for (int ii = 0; ii < 4; ++ii){
        float2 p = bfp2(LD_U32(prb + (tr*4+ii)*66 + j2*2));
        ov0[ii] = fmaf(p.x, va.x, ov0[ii]);
        ov0[ii] = fmaf(p.y, vb.x, ov0[ii]);
        ov1[ii] = fmaf(p.x, va.y, ov1[ii]);
        ov1[ii] = fmaf(p.y, vb.y, ov1[ii]);
      }
    }
    #pragma unroll
    for (int ii = 0; ii < 4; ++ii)
      ST_U32(outh + (tr*4+ii)*34 + tc*2, pack2(ov0[ii], ov1[ii]));
    __syncthreads();

    // ---- partial projection: pj += outh @ proj_w[:, h*32:h*32+32]^T ----
    #pragma unroll 1
    for (int half = 0; half < 2; ++half){
      for (int s = tid; s < 96*16; s += 256){
        int rr = s >> 4, c2 = s & 15;
        float2 v = LDF2(proj_w + (size_t)(half*96+rr)*192 + h*32 + c2*2);
        ST_U32(wtp + rr*34 + c2*2, pack2(v.x, v.y));
      }
      __syncthreads();
      #pragma unroll
      for (int oc3 = 0; oc3 < 3; ++oc3){
        const u16* w0p = wtp + (oc3*32 + tc*2)*34;
        const u16* w1p = w0p + 34;
        int cc = (half*3 + oc3)*2;
        #pragma unroll 2
        for (int k2 = 0; k2 < 16; ++k2){
          float2 w0 = bfp2(LD_U32(w0p + k2*2));
          float2 w1 = bfp2(LD_U32(w1p + k2*2));
          #pragma unroll
          for (int ii = 0; ii < 4; ++ii){
            float2 a = bfp2(LD_U32(outh + (tr*4+ii)*34 + k2*2));
            pj[ii][cc]   = fmaf(a.x, w0.x, pj[ii][cc]);
            pj[ii][cc]   = fmaf(a.y, w0.y, pj[ii][cc]);
            pj[ii][cc+1] = fmaf(a.x, w1.x, pj[ii][cc+1]);
            pj[ii][cc+1] = fmaf(a.y, w1.y, pj[ii][cc+1]);
          }
        }
      }
      __syncthreads();
    }
  } // heads

  // ---- LN1 + residual, scatter back to un-shifted coords (f32 out) ----
  float2 gg[6], bb[6];
  #pragma unroll
  for (int oc = 0; oc < 6; ++oc){
    gg[oc] = LDF2(n1g + oc*32 + tc*2);
    bb[oc] = LDF2(n1b + oc*32 + tc*2);
  }
  #pragma unroll
  for (int ii = 0; ii < 4; ++ii){
    float s1 = 0.f, s2 = 0.f;
    #pragma unroll
    for (int cc = 0; cc < 12; ++cc){ s1 += pj[ii][cc]; s2 = fmaf(pj[ii][cc], pj[ii][cc], s2); }
    #pragma unroll
    for (int mk = 1; mk < 16; mk <<= 1){ s1 += __shfl_xor(s1, mk); s2 += __shfl_xor(s2, mk); }
    float mu = s1 * (1.f/192.f);
    float rs = rsqrtf(s2 * (1.f/192.f) - mu*mu + LN_EPS);
    int t = tr*4 + ii;
    int i = t >> 3, j = t & 7;
    int h0 = ((wh<<3) + i + 4) & 255, w0 = ((ww<<3) + j + 4) & 255;
    size_t base = imgbase + (size_t)(h0*256 + w0)*192;
    #pragma unroll
    for (int oc = 0; oc < 6; ++oc){
      float2 xv = LDF2(x + base + oc*32 + tc*2);
      float y0 = xv.x + (pj[ii][oc*2]   - mu)*rs*gg[oc].x + bb[oc].x;
      float y1 = xv.y + (pj[ii][oc*2+1] - mu)*rs*gg[oc].y + bb[oc].y;
      *(float2*)(x1 + base + oc*32 + tc*2) = make_float2(y0, y1);
    }
  }
}

// =====================================================================
// K2: MLP (fc1 + GELU + fc2) + LN2 + residual, IN-PLACE on xio (f32)
// one block per 64 tokens (4096 blocks), 256 threads
// =====================================================================
__global__ __launch_bounds__(256, 2) void k_mlp(
    float* __restrict__ xio, const float* __restrict__ fc1_w,
    const float* __restrict__ fc1_b, const float* __restrict__ fc2_w,
    const float* __restrict__ fc2_b, const float* __restrict__ n2g,
    const float* __restrict__ n2b)
{
  __shared__ u16 xt[64*194];
  __shared__ u32 reg2[3264];      // 13056 B: wt1[32][194] (12416) / wt2[192][34] (13056)
  __shared__ u16 hbuf[64*34];
  u16* const wt1 = (u16*)reg2;
  u16* const wt2 = (u16*)reg2;

  const int tid = threadIdx.x;
  const int tr = tid >> 4, tc = tid & 15;
  const size_t t0 = (size_t)blockIdx.x * 64;

  for (int s = tid; s < 64*96; s += 256){
    int t = s / 96, c2 = s - t*96;
    float2 v = LDF2(xio + (t0 + t)*192 + c2*2);
    ST_U32(xt + t*194 + c2*2, pack2(v.x, v.y));
  }
  float m[4][12];
  #pragma unroll
  for (int oc = 0; oc < 6; ++oc){
    float2 b2 = LDF2(fc2_b + oc*32 + tc*2);
    #pragma unroll
    for (int ii = 0; ii < 4; ++ii){ m[ii][oc*2] = b2.x; m[ii][oc*2+1] = b2.y; }
  }
  __syncthreads();

  #pragma unroll 1
  for (int hc = 0; hc < 24; ++hc){
    int rbase = hc*32;
    __syncthreads();   // prev fc2 readers of reg2/hbuf are done
    for (int s = tid; s < 32*96; s += 256){
      int rr = s / 96, c2 = s - rr*96;
      float2 v = LDF2(fc1_w + (size_t)(rbase+rr)*192 + c2*2);
      ST_U32(wt1 + rr*194 + c2*2, pack2(v.x, v.y));
    }
    __syncthreads();
    // h chunk: rows 2tc+{0,1} of this 32-row block
    float2 bia = LDF2(fc1_b + rbase + tc*2);
    float acc0[4], acc1[4];
    #pragma unroll
    for (int ii = 0; ii < 4; ++ii){ acc0[ii] = bia.x; acc1[ii] = bia.y; }
    const u16* wr0 = wt1 + (tc*2)*194;
    const u16* wr1 = wr0 + 194;
    const u16* xr  = xt + (tr*4)*194;
    #pragma unroll 4
    for (int k2 = 0; k2 < 96; ++k2){
      float2 w0 = bfp2(LD_U32(wr0 + k2*2));
      float2 w1 = bfp2(LD_U32(wr1 + k2*2));
      #pragma unroll
      for (int ii = 0; ii < 4; ++ii){
        float2 a = bfp2(LD_U32(xr + ii*194 + k2*2));
        acc0[ii] = fmaf(a.x, w0.x, acc0[ii]);
        acc0[ii] = fmaf(a.y, w0.y, acc0[ii]);
        acc1[ii] = fmaf(a.x, w1.x, acc1[ii]);
        acc1[ii] = fmaf(a.y, w1.y, acc1[ii]);
      }
    }
    #pragma unroll
    for (int ii = 0; ii < 4; ++ii)
      ST_U32(hbuf + (tr*4+ii)*34 + tc*2, pack2(gelu_f(acc0[ii]), gelu_f(acc1[ii])));
    __syncthreads();   // hbuf visible, wt1 reads done
    for (int s = tid; s < 192*16; s += 256){
      int rr = s >> 4, c2 = s & 15;
      float2 v = LDF2(fc2_w + (size_t)rr*768 + rbase + c2*2);
      ST_U32(wt2 + rr*34 + c2*2, pack2(v.x, v.y));
    }
    __syncthreads();
    #pragma unroll
    for (int oc = 0; oc < 6; ++oc){
      const u16* w0p = wt2 + (oc*32 + tc*2)*34;
      const u16* w1p = w0p + 34;
      #pragma unroll 2
      for (int k2 = 0; k2 < 16; ++k2){
        float2 w0 = bfp2(LD_U32(w0p + k2*2));
        float2 w1 = bfp2(LD_U32(w1p + k2*2));
        #pragma unroll
        for (int ii = 0; ii < 4; ++ii){
          float2 a = bfp2(LD_U32(hbuf + (tr*4+ii)*34 + k2*2));
          m[ii][oc*2]   = fmaf(a.x, w0.x, m[ii][oc*2]);
          m[ii][oc*2]   = fmaf(a.y, w0.y, m[ii][oc*2]);
          m[ii][oc*2+1] = fmaf(a.x, w1.x, m[ii][oc*2+1]);
          m[ii][oc*2+1] = fmaf(a.y, w1.y, m[ii][oc*2+1]);
        }
      }
    }
  }

  // ---- LN2 + residual (read f32 x1 then overwrite; element-disjoint per thread) ----
  float2 gg[6], bb[6];
  #pragma unroll
  for (int oc = 0; oc < 6; ++oc){
    gg[oc] = LDF2(n2g + oc*32 + tc*2);
    bb[oc] = LDF2(n2b + oc*32 + tc*2);
  }
  #pragma unroll
  for (int ii = 0; ii < 4; ++ii){
    float s1 = 0.f, s2 = 0.f;
    #pragma unroll
    for (int cc = 0; cc < 12; ++cc){ s1 += m[ii][cc]; s2 = fmaf(m[ii][cc], m[ii][cc], s2); }
    #pragma unroll
    for (int mk = 1; mk < 16; mk <<= 1){ s1 += __shfl_xor(s1, mk); s2 += __shfl_xor(s2, mk); }
    float mu = s1 * (1.f/192.f);
    float rs = rsqrtf(s2 * (1.f/192.f) - mu*mu + LN_EPS);
    size_t base = (t0 + tr*4 + ii)*192;
    #pragma unroll
    for (int oc = 0; oc < 6; ++oc){
      float2 xv = LDF2(xio + base + oc*32 + tc*2);
      float y0 = xv.x + (m[ii][oc*2]   - mu)*rs*gg[oc].x + bb[oc].x;
      float y1 = xv.y + (m[ii][oc*2+1] - mu)*rs*gg[oc].y + bb[oc].y;
      *(float2*)(xio + base + oc*32 + tc*2) = make_float2(y0, y1);
    }
  }
}

extern "C" void kernel_launch(void* const* d_in, const int* in_sizes, int n_in,
                              void* d_out, int out_size, void* d_ws, size_t ws_size,
                              hipStream_t stream)
{
  const float* x      = (const float*)d_in[0];
  const float* mask   = (const float*)d_in[1];
  const int*   relidx = (const int*)d_in[2];
  const float* qkv_w  = (const float*)d_in[3];
  const float* qkv_b  = (const float*)d_in[4];
  const float* proj_w = (const float*)d_in[5];
  const float* proj_b = (const float*)d_in[6];
  const float* rpb    = (const float*)d_in[7];
  const float* n1g    = (const float*)d_in[8];
  const float* n1b    = (const float*)d_in[9];
  const float* n2g    = (const float*)d_in[10];
  const float* n2b    = (const float*)d_in[11];
  const float* fc1_w  = (const float*)d_in[12];
  const float* fc1_b  = (const float*)d_in[13];
  const float* fc2_w  = (const float*)d_in[14];
  const float* fc2_b  = (const float*)d_in[15];
  float* xio = (float*)d_out;

  k_attn<<<dim3(4096), dim3(256), 0, stream>>>(x, mask, relidx, qkv_w, qkv_b,
      proj_w, proj_b, rpb, n1g, n1b, xio);
  k_mlp<<<dim3(4096), dim3(256), 0, stream>>>(xio, fc1_w, fc1_b, fc2_w, fc2_b,
      n2g, n2b);
}

// Round 3
// 1722.184 us; speedup vs baseline: 3.3666x; 3.3666x over previous
//
#include <hip/hip_runtime.h>
#include <hip/hip_bf16.h>
#include <math.h>

typedef unsigned short u16;
typedef unsigned int   u32;
typedef __attribute__((ext_vector_type(8))) short bf16x8;   // 8 bf16 = 4 VGPR
typedef __attribute__((ext_vector_type(4))) float f32x4;

__device__ __forceinline__ float2 bfp2(u32 p){
  return make_float2(__uint_as_float(p<<16), __uint_as_float(p & 0xffff0000u));
}
__device__ __forceinline__ u16 f2bf(float f){
  u32 u = __float_as_uint(f);
  u += 0x7fffu + ((u>>16)&1u);          // RNE; inputs never NaN
  return (u16)(u>>16);
}
__device__ __forceinline__ u32 pack2(float a, float b){
  return (u32)f2bf(a) | ((u32)f2bf(b)<<16);
}
__device__ __forceinline__ float2 LDF2(const float* p){ return *(const float2*)p; }
__device__ __forceinline__ float gelu_f(float v){
  // tanh-form GELU: |err| < ~1e-3 abs, far under threshold; exact erff is ~3x VALU cost
  float t = __expf(1.5957691216057308f * fmaf(0.044715f*v, v*v, v));
  return v - v/(t + 1.0f);
}

#define LD_U32(p)   (*(const u32*)(p))
#define ST_U32(p,v) (*(u32*)(p) = (v))
#define MFMA16(a,b,c) __builtin_amdgcn_mfma_f32_16x16x32_bf16((a),(b),(c),0,0,0)

__device__ __forceinline__ bf16x8 ldsfrag(const u16* p){ return *(const bf16x8*)p; }
__device__ __forceinline__ bf16x8 cvt8(const float* p){
  float4 a = *(const float4*)p;
  float4 b = *(const float4*)(p+4);
  bf16x8 r;
  r[0] = (short)f2bf(a.x); r[1] = (short)f2bf(a.y);
  r[2] = (short)f2bf(a.z); r[3] = (short)f2bf(a.w);
  r[4] = (short)f2bf(b.x); r[5] = (short)f2bf(b.y);
  r[6] = (short)f2bf(b.z); r[7] = (short)f2bf(b.w);
  return r;
}

constexpr float SCALE_Q = 0.17677669529663687f;  // 32^-0.5
constexpr float LN_EPS  = 1e-5f;

// =====================================================================
// K1: shifted-window attention + proj + LN1 + residual -> x1 (f32 = d_out)
// one block per window (4096 blocks), 256 threads = 4 waves
// qkv & proj on MFMA; QK^T/softmax/PV stay VALU (13 GF only)
// =====================================================================
__global__ __launch_bounds__(256, 3) void k_attn(
    const float* __restrict__ x, const float* __restrict__ mask,
    const int* __restrict__ relidx, const float* __restrict__ qkv_w,
    const float* __restrict__ qkv_b, const float* __restrict__ proj_w,
    const float* __restrict__ proj_b, const float* __restrict__ rpb,
    const float* __restrict__ n1g, const float* __restrict__ n1b,
    float* __restrict__ x1)
{
  __shared__ __align__(16) u16 xw[64*200];    // window tokens bf16, stride 200 (b128-aligned)
  __shared__ __align__(16) u16 qkvh[64*98];   // per-head q|k|v
  __shared__ __align__(16) u16 prb[64*66];    // probs
  __shared__ __align__(16) u16 outh[64*40];   // per-head PV out (stride 40 => aligned frags)
  __shared__ float lnred[64*8];               // per-token (s1,s2) x 4 waves

  const int tid  = threadIdx.x;
  const int wave = tid >> 6, lane = tid & 63;
  const int kg   = lane >> 4, l15 = lane & 15;   // mfma k-group / row-col lane
  const int tr   = tid >> 4,  tc  = tid & 15;    // VALU-attn 16x16 grid
  const int wi = blockIdx.x;
  const int b  = wi >> 10, wm = wi & 1023;
  const int wh = wm >> 5,  ww = wm & 31;
  const size_t imgbase = (size_t)b * (256*256*192);

  // ---- gather shifted window (roll -4,-4), f32 -> bf16 ----
  for (int s = tid; s < 64*96; s += 256){
    int t = s / 96, c2 = s - t*96;
    int i = t >> 3, j = t & 7;
    int h0 = ((wh<<3) + i + 4) & 255;
    int w0 = ((ww<<3) + j + 4) & 255;
    float2 v = LDF2(x + imgbase + (size_t)(h0*256 + w0)*192 + c2*2);
    ST_U32(xw + t*200 + c2*2, pack2(v.x, v.y));
  }

  // proj accumulators: wave owns output cols [wave*48, wave*48+48), all 4 m-tiles
  f32x4 pj[4][3];
  #pragma unroll
  for (int mt = 0; mt < 4; ++mt)
    #pragma unroll
    for (int nt = 0; nt < 3; ++nt){
      float bv = proj_b[wave*48 + nt*16 + l15];
      pj[mt][nt] = {bv, bv, bv, bv};
    }
  __syncthreads();

  const int qmt = wave;   // qkv GEMM: wave owns m-tile = wave
  #pragma unroll 1
  for (int h = 0; h < 6; ++h){
    // ---- step1: qkv MFMA: 6 n-tiles (q0,q1,k0,k1,v0,v1), K=192 ----
    f32x4 qa[6];
    #pragma unroll
    for (int nt = 0; nt < 6; ++nt){
      float bv = qkv_b[(nt>>1)*192 + h*32 + (nt&1)*16 + l15];
      qa[nt] = {bv, bv, bv, bv};
    }
    #pragma unroll 1
    for (int kt = 0; kt < 6; ++kt){
      bf16x8 af = ldsfrag(xw + (qmt*16 + l15)*200 + kt*32 + kg*8);
      #pragma unroll
      for (int nt = 0; nt < 6; ++nt){
        bf16x8 bfr = cvt8(qkv_w + (size_t)((nt>>1)*192 + h*32 + (nt&1)*16 + l15)*192 + kt*32 + kg*8);
        qa[nt] = MFMA16(af, bfr, qa[nt]);
      }
    }
    #pragma unroll
    for (int nt = 0; nt < 6; ++nt){
      float scl = (nt < 2) ? SCALE_Q : 1.0f;
      #pragma unroll
      for (int r = 0; r < 4; ++r)
        qkvh[(qmt*16 + kg*4 + r)*98 + (nt>>1)*32 + (nt&1)*16 + l15] = f2bf(qa[nt][r]*scl);
    }
    __syncthreads();

    // ---- step2: logits + softmax (VALU) ----
    float sl[4][4];
    #pragma unroll
    for (int ii = 0; ii < 4; ++ii)
      #pragma unroll
      for (int jj = 0; jj < 4; ++jj) sl[ii][jj] = 0.f;
    #pragma unroll 2
    for (int d2 = 0; d2 < 16; ++d2){
      float2 kv[4];
      #pragma unroll
      for (int jj = 0; jj < 4; ++jj)
        kv[jj] = bfp2(LD_U32(qkvh + (tc*4+jj)*98 + 32 + d2*2));
      #pragma unroll
      for (int ii = 0; ii < 4; ++ii){
        float2 qv = bfp2(LD_U32(qkvh + (tr*4+ii)*98 + d2*2));
        #pragma unroll
        for (int jj = 0; jj < 4; ++jj){
          sl[ii][jj] = fmaf(qv.x, kv[jj].x, sl[ii][jj]);
          sl[ii][jj] = fmaf(qv.y, kv[jj].y, sl[ii][jj]);
        }
      }
    }
    const size_t mbase = (size_t)wm * 4096;
    #pragma unroll
    for (int ii = 0; ii < 4; ++ii){
      int i = tr*4 + ii;
      #pragma unroll
      for (int jj = 0; jj < 4; ++jj){
        int j = tc*4 + jj;
        sl[ii][jj] += rpb[relidx[i*64 + j]*6 + h] + mask[mbase + i*64 + j];
      }
    }
    float inv_[4];
    #pragma unroll
    for (int ii = 0; ii < 4; ++ii){
      float m0 = fmaxf(fmaxf(sl[ii][0], sl[ii][1]), fmaxf(sl[ii][2], sl[ii][3]));
      #pragma unroll
      for (int mk = 1; mk < 16; mk <<= 1) m0 = fmaxf(m0, __shfl_xor(m0, mk));
      float s = 0.f;
      #pragma unroll
      for (int jj = 0; jj < 4; ++jj){ sl[ii][jj] = __expf(sl[ii][jj] - m0); s += sl[ii][jj]; }
      #pragma unroll
      for (int mk = 1; mk < 16; mk <<= 1) s += __shfl_xor(s, mk);
      inv_[ii] = 1.0f / s;
    }
    #pragma unroll
    for (int ii = 0; ii < 4; ++ii){
      ST_U32(prb + (tr*4+ii)*66 + tc*4,     pack2(sl[ii][0]*inv_[ii], sl[ii][1]*inv_[ii]));
      ST_U32(prb + (tr*4+ii)*66 + tc*4 + 2, pack2(sl[ii][2]*inv_[ii], sl[ii][3]*inv_[ii]));
    }
    __syncthreads();

    // ---- step3: PV (VALU) -> outh ----
    float ov0[4] = {0,0,0,0}, ov1[4] = {0,0,0,0};
    #pragma unroll 2
    for (int j2 = 0; j2 < 32; ++j2){
      float2 va = bfp2(LD_U32(qkvh + (j2*2  )*98 + 64 + tc*2));
      float2 vb = bfp2(LD_U32(qkvh + (j2*2+1)*98 + 64 + tc*2));
      #pragma unroll
      for (int ii = 0; ii < 4; ++ii){
        float2 p = bfp2(LD_U32(prb + (tr*4+ii)*66 + j2*2));
        ov0[ii] = fmaf(p.x, va.x, ov0[ii]);
        ov0[ii] = fmaf(p.y, vb.x, ov0[ii]);
        ov1[ii] = fmaf(p.x, va.y, ov1[ii]);
        ov1[ii] = fmaf(p.y, vb.y, ov1[ii]);
      }
    }
    #pragma unroll
    for (int ii = 0; ii < 4; ++ii)
      ST_U32(outh + (tr*4+ii)*40 + tc*2, pack2(ov0[ii], ov1[ii]));
    __syncthreads();

    // ---- step4: proj MFMA partial (K=32 this head) ----
    #pragma unroll
    for (int mt = 0; mt < 4; ++mt){
      bf16x8 af = ldsfrag(outh + (mt*16 + l15)*40 + kg*8);
      #pragma unroll
      for (int nt = 0; nt < 3; ++nt){
        bf16x8 bfr = cvt8(proj_w + (size_t)(wave*48 + nt*16 + l15)*192 + h*32 + kg*8);
        pj[mt][nt] = MFMA16(af, bfr, pj[mt][nt]);
      }
    }
  } // heads

  // ---- LN1 + residual, scatter to un-shifted coords ----
  float gv[3], bv2[3];
  #pragma unroll
  for (int nt = 0; nt < 3; ++nt){
    int c = wave*48 + nt*16 + l15;
    gv[nt] = n1g[c]; bv2[nt] = n1b[c];
  }
  #pragma unroll
  for (int mt = 0; mt < 4; ++mt)
    #pragma unroll
    for (int r = 0; r < 4; ++r){
      float s1 = pj[mt][0][r] + pj[mt][1][r] + pj[mt][2][r];
      float s2 = pj[mt][0][r]*pj[mt][0][r] + pj[mt][1][r]*pj[mt][1][r] + pj[mt][2][r]*pj[mt][2][r];
      #pragma unroll
      for (int mk = 1; mk < 16; mk <<= 1){ s1 += __shfl_xor(s1, mk); s2 += __shfl_xor(s2, mk); }
      if (l15 == 0){
        int t = mt*16 + kg*4 + r;
        lnred[t*8 + wave*2]     = s1;
        lnred[t*8 + wave*2 + 1] = s2;
      }
    }
  __syncthreads();
  #pragma unroll
  for (int mt = 0; mt < 4; ++mt)
    #pragma unroll 1
    for (int r = 0; r < 4; ++r){
      int t = mt*16 + kg*4 + r;
      float a1 = lnred[t*8+0] + lnred[t*8+2] + lnred[t*8+4] + lnred[t*8+6];
      float a2 = lnred[t*8+1] + lnred[t*8+3] + lnred[t*8+5] + lnred[t*8+7];
      float mu = a1 * (1.f/192.f);
      float rs = rsqrtf(a2 * (1.f/192.f) - mu*mu + LN_EPS);
      int i = t >> 3, j = t & 7;
      int h0 = ((wh<<3) + i + 4) & 255, w0 = ((ww<<3) + j + 4) & 255;
      size_t base = imgbase + (size_t)(h0*256 + w0)*192;
      #pragma unroll
      for (int nt = 0; nt < 3; ++nt){
        int c = wave*48 + nt*16 + l15;
        x1[base + c] = x[base + c] + (pj[mt][nt][r] - mu)*rs*gv[nt] + bv2[nt];
      }
    }
}

// =====================================================================
// K2: MLP (fc1 + GELU + fc2) + LN2 + residual, IN-PLACE on xio (f32)
// one block per 64 tokens (4096 blocks), 256 threads = 4 waves, MFMA
// =====================================================================
__global__ __launch_bounds__(256, 3) void k_mlp(
    float* xio, const float* __restrict__ fc1_w,
    const float* __restrict__ fc1_b, const float* __restrict__ fc2_w,
    const float* __restrict__ fc2_b, const float* __restrict__ n2g,
    const float* __restrict__ n2b)
{
  __shared__ __align__(16) u16 xt[64*200];   // x1 tokens bf16
  __shared__ __align__(16) u16 hl[64*200];   // hidden chunk bf16
  __shared__ float lnred[64*8];

  const int tid  = threadIdx.x;
  const int wave = tid >> 6, lane = tid & 63;
  const int kg   = lane >> 4, l15 = lane & 15;
  const size_t t0 = (size_t)blockIdx.x * 64;

  for (int s = tid; s < 64*96; s += 256){
    int t = s / 96, c2 = s - t*96;
    float2 v = LDF2(xio + (t0 + t)*192 + c2*2);
    ST_U32(xt + t*200 + c2*2, pack2(v.x, v.y));
  }
  f32x4 m2[4][3];
  #pragma unroll
  for (int mt = 0; mt < 4; ++mt)
    #pragma unroll
    for (int nt = 0; nt < 3; ++nt){
      float bv = fc2_b[wave*48 + nt*16 + l15];
      m2[mt][nt] = {bv, bv, bv, bv};
    }
  __syncthreads();

  #pragma unroll 1
  for (int c = 0; c < 4; ++c){
    // ---- fc1: h_chunk[:, wave*48 .. +48) ----
    f32x4 a1[4][3];
    #pragma unroll
    for (int mt = 0; mt < 4; ++mt)
      #pragma unroll
      for (int nt = 0; nt < 3; ++nt){
        float bv = fc1_b[c*192 + wave*48 + nt*16 + l15];
        a1[mt][nt] = {bv, bv, bv, bv};
      }
    #pragma unroll 1
    for (int kt = 0; kt < 6; ++kt){
      bf16x8 af[4];
      #pragma unroll
      for (int mt = 0; mt < 4; ++mt)
        af[mt] = ldsfrag(xt + (mt*16 + l15)*200 + kt*32 + kg*8);
      #pragma unroll
      for (int nt = 0; nt < 3; ++nt){
        bf16x8 bfr = cvt8(fc1_w + (size_t)(c*192 + wave*48 + nt*16 + l15)*192 + kt*32 + kg*8);
        #pragma unroll
        for (int mt = 0; mt < 4; ++mt)
          a1[mt][nt] = MFMA16(af[mt], bfr, a1[mt][nt]);
      }
    }
    // GELU + scatter C-layout -> hl
    #pragma unroll
    for (int mt = 0; mt < 4; ++mt)
      #pragma unroll
      for (int nt = 0; nt < 3; ++nt)
        #pragma unroll
        for (int r = 0; r < 4; ++r)
          hl[(mt*16 + kg*4 + r)*200 + wave*48 + nt*16 + l15] = f2bf(gelu_f(a1[mt][nt][r]));
    __syncthreads();

    // ---- fc2 partial over this chunk (K=192) ----
    #pragma unroll 1
    for (int kt = 0; kt < 6; ++kt){
      bf16x8 af[4];
      #pragma unroll
      for (int mt = 0; mt < 4; ++mt)
        af[mt] = ldsfrag(hl + (mt*16 + l15)*200 + kt*32 + kg*8);
      #pragma unroll
      for (int nt = 0; nt < 3; ++nt){
        bf16x8 bfr = cvt8(fc2_w + (size_t)(wave*48 + nt*16 + l15)*768 + c*192 + kt*32 + kg*8);
        #pragma unroll
        for (int mt = 0; mt < 4; ++mt)
          m2[mt][nt] = MFMA16(af[mt], bfr, m2[mt][nt]);
      }
    }
    __syncthreads();   // hl consumed; safe to overwrite next chunk
  }

  // ---- LN2 + residual (in-place; each element RMW by its own thread) ----
  float gv[3], bv2[3];
  #pragma unroll
  for (int nt = 0; nt < 3; ++nt){
    int cc = wave*48 + nt*16 + l15;
    gv[nt] = n2g[cc]; bv2[nt] = n2b[cc];
  }
  #pragma unroll
  for (int mt = 0; mt < 4; ++mt)
    #pragma unroll
    for (int r = 0; r < 4; ++r){
      float s1 = m2[mt][0][r] + m2[mt][1][r] + m2[mt][2][r];
      float s2 = m2[mt][0][r]*m2[mt][0][r] + m2[mt][1][r]*m2[mt][1][r] + m2[mt][2][r]*m2[mt][2][r];
      #pragma unroll
      for (int mk = 1; mk < 16; mk <<= 1){ s1 += __shfl_xor(s1, mk); s2 += __shfl_xor(s2, mk); }
      if (l15 == 0){
        int t = mt*16 + kg*4 + r;
        lnred[t*8 + wave*2]     = s1;
        lnred[t*8 + wave*2 + 1] = s2;
      }
    }
  __syncthreads();
  #pragma unroll
  for (int mt = 0; mt < 4; ++mt)
    #pragma unroll 1
    for (int r = 0; r < 4; ++r){
      int t = mt*16 + kg*4 + r;
      float a1s = lnred[t*8+0] + lnred[t*8+2] + lnred[t*8+4] + lnred[t*8+6];
      float a2s = lnred[t*8+1] + lnred[t*8+3] + lnred[t*8+5] + lnred[t*8+7];
      float mu = a1s * (1.f/192.f);
      float rs = rsqrtf(a2s * (1.f/192.f) - mu*mu + LN_EPS);
      size_t base = (t0 + t)*192;
      #pragma unroll
      for (int nt = 0; nt < 3; ++nt){
        int cc = wave*48 + nt*16 + l15;
        xio[base + cc] = xio[base + cc] + (m2[mt][nt][r] - mu)*rs*gv[nt] + bv2[nt];
      }
    }
}

extern "C" void kernel_launch(void* const* d_in, const int* in_sizes, int n_in,
                              void* d_out, int out_size, void* d_ws, size_t ws_size,
                              hipStream_t stream)
{
  const float* x      = (const float*)d_in[0];
  const float* mask   = (const float*)d_in[1];
  const int*   relidx = (const int*)d_in[2];
  const float* qkv_w  = (const float*)d_in[3];
  const float* qkv_b  = (const float*)d_in[4];
  const float* proj_w = (const float*)d_in[5];
  const float* proj_b = (const float*)d_in[6];
  const float* rpb    = (const float*)d_in[7];
  const float* n1g    = (const float*)d_in[8];
  const float* n1b    = (const float*)d_in[9];
  const float* n2g    = (const float*)d_in[10];
  const float* n2b    = (const float*)d_in[11];
  const float* fc1_w  = (const float*)d_in[12];
  const float* fc1_b  = (const float*)d_in[13];
  const float* fc2_w  = (const float*)d_in[14];
  const float* fc2_b  = (const float*)d_in[15];
  float* xio = (float*)d_out;

  k_attn<<<dim3(4096), dim3(256), 0, stream>>>(x, mask, relidx, qkv_w, qkv_b,
      proj_w, proj_b, rpb, n1g, n1b, xio);
  k_mlp<<<dim3(4096), dim3(256), 0, stream>>>(xio, fc1_w, fc1_b, fc2_w, fc2_b,
      n2g, n2b);
}

// Round 4
// 1037.430 us; speedup vs baseline: 5.5888x; 1.6600x over previous
//
#include <hip/hip_runtime.h>
#include <hip/hip_bf16.h>
#include <math.h>

typedef unsigned short u16;
typedef unsigned int   u32;
typedef __attribute__((ext_vector_type(8))) short bf16x8;   // 8 bf16 = 4 VGPR
typedef __attribute__((ext_vector_type(4))) float f32x4;

__device__ __forceinline__ u16 f2bf(float f){
  u32 u = __float_as_uint(f);
  u += 0x7fffu + ((u>>16)&1u);          // RNE; inputs never NaN
  return (u16)(u>>16);
}
__device__ __forceinline__ u32 pack2(float a, float b){
  return (u32)f2bf(a) | ((u32)f2bf(b)<<16);
}
__device__ __forceinline__ float2 LDF2(const float* p){ return *(const float2*)p; }
__device__ __forceinline__ float gelu_f(float v){
  float t = __expf(1.5957691216057308f * fmaf(0.044715f*v, v*v, v));
  return v - v/(t + 1.0f);
}

#define ST_U32(p,v) (*(u32*)(p) = (v))
#define MFMA16(a,b,c) __builtin_amdgcn_mfma_f32_16x16x32_bf16((a),(b),(c),0,0,0)

__device__ __forceinline__ bf16x8 ldsfrag(const u16* p){ return *(const bf16x8*)p; }
__device__ __forceinline__ bf16x8 gfrag(const u16* p){ return *(const bf16x8*)p; }

constexpr float SCALE_Q = 0.17677669529663687f;  // 32^-0.5
constexpr float LN_EPS  = 1e-5f;

// ws element counts (u16)
#define NQKV 110592
#define NPRJ 36864
#define NFC  147456

// =====================================================================
// K0: weight f32->bf16 conversion + rpb gather into dense map
// =====================================================================
__global__ void k_prep(const float* __restrict__ qkv_w, const float* __restrict__ proj_w,
                       const float* __restrict__ fc1_w, const float* __restrict__ fc2_w,
                       const float* __restrict__ rpb, const int* __restrict__ relidx,
                       u16* __restrict__ qkv_bf, u16* __restrict__ proj_bf,
                       u16* __restrict__ fc1_bf, u16* __restrict__ fc2_bf,
                       float* __restrict__ rpbm)
{
  int stride = gridDim.x * blockDim.x;
  int t = blockIdx.x * blockDim.x + threadIdx.x;
  for (int i = t; i < NQKV; i += stride) qkv_bf[i] = f2bf(qkv_w[i]);
  for (int i = t; i < NPRJ; i += stride) proj_bf[i] = f2bf(proj_w[i]);
  for (int i = t; i < NFC;  i += stride) fc1_bf[i]  = f2bf(fc1_w[i]);
  for (int i = t; i < NFC;  i += stride) fc2_bf[i]  = f2bf(fc2_w[i]);
  for (int i = t; i < 6*4096; i += stride){
    int h = i >> 12, ij = i & 4095;
    rpbm[i] = rpb[relidx[ij]*6 + h];
  }
}

// =====================================================================
// K1: shifted-window attention + proj + LN1 + residual -> x1 (f32 = d_out)
// one block per window (4096 blocks), 4 waves; all-MFMA
// =====================================================================
__global__ __launch_bounds__(256, 3) void k_attn(
    const float* __restrict__ x, const float* __restrict__ mask,
    const float* __restrict__ rpbm, const u16* __restrict__ qkv_bf,
    const float* __restrict__ qkv_b, const u16* __restrict__ proj_bf,
    const float* __restrict__ proj_b, const float* __restrict__ n1g,
    const float* __restrict__ n1b, float* __restrict__ x1)
{
  __shared__ __align__(16) u16 xw[64*200];    // window tokens bf16
  __shared__ __align__(16) u16 qkvh[64*72];   // per-token q(0..31)|k(32..63)
  __shared__ __align__(16) u16 vT[32*72];     // V transposed [d][token]
  __shared__ __align__(16) u16 prb[64*72];    // P row-major
  __shared__ __align__(16) u16 outh[64*40];   // per-head PV out
  float* lnred = (float*)outh;                // alias: used only after last proj

  const int tid  = threadIdx.x;
  const int wave = tid >> 6, lane = tid & 63;
  const int kg   = lane >> 4, l15 = lane & 15;
  const int wi = blockIdx.x;
  const int b  = wi >> 10, wm = wi & 1023;
  const int wh = wm >> 5,  ww = wm & 31;
  const size_t imgbase = (size_t)b * (256*256*192);

  // ---- gather shifted window (roll -4,-4), f32 -> bf16 ----
  for (int s = tid; s < 64*96; s += 256){
    int t = s / 96, c2 = s - t*96;
    int i = t >> 3, j = t & 7;
    int h0 = ((wh<<3) + i + 4) & 255;
    int w0 = ((ww<<3) + j + 4) & 255;
    float2 v = LDF2(x + imgbase + (size_t)(h0*256 + w0)*192 + c2*2);
    ST_U32(xw + t*200 + c2*2, pack2(v.x, v.y));
  }

  // proj accumulators: wave owns output cols [wave*48, +48), all 4 m-tiles
  f32x4 pj[4][3];
  #pragma unroll
  for (int mt = 0; mt < 4; ++mt)
    #pragma unroll
    for (int nt = 0; nt < 3; ++nt){
      float bv = proj_b[wave*48 + nt*16 + l15];
      pj[mt][nt] = {bv, bv, bv, bv};
    }
  __syncthreads();

  #pragma unroll 1
  for (int h = 0; h < 6; ++h){
    // ---- step1: qkv MFMA (m-tile = wave), 6 n-tiles, K=192 ----
    f32x4 qa[6];
    #pragma unroll
    for (int nt = 0; nt < 6; ++nt){
      float bv = qkv_b[(nt>>1)*192 + h*32 + (nt&1)*16 + l15];
      qa[nt] = {bv, bv, bv, bv};
    }
    #pragma unroll 2
    for (int kt = 0; kt < 6; ++kt){
      bf16x8 af = ldsfrag(xw + (wave*16 + l15)*200 + kt*32 + kg*8);
      #pragma unroll
      for (int nt = 0; nt < 6; ++nt){
        bf16x8 bfr = gfrag(qkv_bf + ((nt>>1)*192 + h*32 + (nt&1)*16 + l15)*192 + kt*32 + kg*8);
        qa[nt] = MFMA16(af, bfr, qa[nt]);
      }
    }
    #pragma unroll
    for (int nt = 0; nt < 2; ++nt)
      #pragma unroll
      for (int r = 0; r < 4; ++r)
        qkvh[(wave*16 + kg*4 + r)*72 + nt*16 + l15] = f2bf(qa[nt][r]*SCALE_Q);
    #pragma unroll
    for (int nt = 2; nt < 4; ++nt)
      #pragma unroll
      for (int r = 0; r < 4; ++r)
        qkvh[(wave*16 + kg*4 + r)*72 + 32 + (nt-2)*16 + l15] = f2bf(qa[nt][r]);
    #pragma unroll
    for (int nt = 4; nt < 6; ++nt)
      #pragma unroll
      for (int r = 0; r < 4; ++r)
        vT[((nt-4)*16 + l15)*72 + wave*16 + kg*4 + r] = f2bf(qa[nt][r]);
    __syncthreads();

    // ---- step2: QK^T MFMA (rows = wave's 16 tokens), +rpb+mask, softmax ----
    f32x4 at[4];
    {
      const f32x4 z = {0.f, 0.f, 0.f, 0.f};
      bf16x8 qf = ldsfrag(qkvh + (wave*16 + l15)*72 + kg*8);
      #pragma unroll
      for (int nt = 0; nt < 4; ++nt){
        bf16x8 kf = ldsfrag(qkvh + (nt*16 + l15)*72 + 32 + kg*8);
        at[nt] = MFMA16(qf, kf, z);
      }
    }
    {
      const float* rb = rpbm + h*4096;
      const float* mb = mask + (size_t)wm*4096;
      #pragma unroll
      for (int nt = 0; nt < 4; ++nt)
        #pragma unroll
        for (int r = 0; r < 4; ++r){
          int idx = (wave*16 + kg*4 + r)*64 + nt*16 + l15;
          at[nt][r] += rb[idx] + mb[idx];
        }
    }
    #pragma unroll
    for (int r = 0; r < 4; ++r){
      float m0 = fmaxf(fmaxf(at[0][r], at[1][r]), fmaxf(at[2][r], at[3][r]));
      #pragma unroll
      for (int mk = 1; mk < 16; mk <<= 1) m0 = fmaxf(m0, __shfl_xor(m0, mk));
      float s = 0.f;
      #pragma unroll
      for (int nt = 0; nt < 4; ++nt){ at[nt][r] = __expf(at[nt][r] - m0); s += at[nt][r]; }
      #pragma unroll
      for (int mk = 1; mk < 16; mk <<= 1) s += __shfl_xor(s, mk);
      float inv = 1.0f / s;
      #pragma unroll
      for (int nt = 0; nt < 4; ++nt) at[nt][r] *= inv;
    }
    #pragma unroll
    for (int nt = 0; nt < 4; ++nt)
      #pragma unroll
      for (int r = 0; r < 4; ++r)
        prb[(wave*16 + kg*4 + r)*72 + nt*16 + l15] = f2bf(at[nt][r]);
    // (prb rows are wave-local: compiler's lgkmcnt ordering suffices, no barrier)

    // ---- step3: PV MFMA: O[wave's 16 rows][32 d], K=64 ----
    {
      f32x4 ov[2] = {{0,0,0,0},{0,0,0,0}};
      #pragma unroll
      for (int kt = 0; kt < 2; ++kt){
        bf16x8 pf = ldsfrag(prb + (wave*16 + l15)*72 + kt*32 + kg*8);
        #pragma unroll
        for (int nt = 0; nt < 2; ++nt){
          bf16x8 vf = ldsfrag(vT + (nt*16 + l15)*72 + kt*32 + kg*8);
          ov[nt] = MFMA16(pf, vf, ov[nt]);
        }
      }
      #pragma unroll
      for (int nt = 0; nt < 2; ++nt)
        #pragma unroll
        for (int r = 0; r < 4; ++r)
          outh[(wave*16 + kg*4 + r)*40 + nt*16 + l15] = f2bf(ov[nt][r]);
    }
    __syncthreads();

    // ---- step4: proj MFMA partial (K=32 this head) ----
    {
      bf16x8 pw[3];
      #pragma unroll
      for (int nt = 0; nt < 3; ++nt)
        pw[nt] = gfrag(proj_bf + (wave*48 + nt*16 + l15)*192 + h*32 + kg*8);
      #pragma unroll
      for (int mt = 0; mt < 4; ++mt){
        bf16x8 af = ldsfrag(outh + (mt*16 + l15)*40 + kg*8);
        #pragma unroll
        for (int nt = 0; nt < 3; ++nt)
          pj[mt][nt] = MFMA16(af, pw[nt], pj[mt][nt]);
      }
    }
    __syncthreads();
  } // heads

  // ---- LN1 + residual, scatter to un-shifted coords ----
  float gv[3], bv2[3];
  #pragma unroll
  for (int nt = 0; nt < 3; ++nt){
    int c = wave*48 + nt*16 + l15;
    gv[nt] = n1g[c]; bv2[nt] = n1b[c];
  }
  #pragma unroll
  for (int mt = 0; mt < 4; ++mt)
    #pragma unroll
    for (int r = 0; r < 4; ++r){
      float s1 = pj[mt][0][r] + pj[mt][1][r] + pj[mt][2][r];
      float s2 = pj[mt][0][r]*pj[mt][0][r] + pj[mt][1][r]*pj[mt][1][r] + pj[mt][2][r]*pj[mt][2][r];
      #pragma unroll
      for (int mk = 1; mk < 16; mk <<= 1){ s1 += __shfl_xor(s1, mk); s2 += __shfl_xor(s2, mk); }
      if (l15 == 0){
        int t = mt*16 + kg*4 + r;
        lnred[t*8 + wave*2]     = s1;
        lnred[t*8 + wave*2 + 1] = s2;
      }
    }
  __syncthreads();
  #pragma unroll
  for (int mt = 0; mt < 4; ++mt)
    #pragma unroll 1
    for (int r = 0; r < 4; ++r){
      int t = mt*16 + kg*4 + r;
      float a1 = lnred[t*8+0] + lnred[t*8+2] + lnred[t*8+4] + lnred[t*8+6];
      float a2 = lnred[t*8+1] + lnred[t*8+3] + lnred[t*8+5] + lnred[t*8+7];
      float mu = a1 * (1.f/192.f);
      float rs = rsqrtf(a2 * (1.f/192.f) - mu*mu + LN_EPS);
      int i = t >> 3, j = t & 7;
      int h0 = ((wh<<3) + i + 4) & 255, w0 = ((ww<<3) + j + 4) & 255;
      size_t base = imgbase + (size_t)(h0*256 + w0)*192;
      #pragma unroll
      for (int nt = 0; nt < 3; ++nt){
        int c = wave*48 + nt*16 + l15;
        x1[base + c] = x[base + c] + (pj[mt][nt][r] - mu)*rs*gv[nt] + bv2[nt];
      }
    }
}

// =====================================================================
// K2: MLP (fc1 + GELU + fc2) + LN2 + residual, IN-PLACE on xio (f32)
// one block per 64 tokens (4096 blocks), 4 waves, MFMA, bf16 weights
// =====================================================================
__global__ __launch_bounds__(256, 3) void k_mlp(
    float* xio, const u16* __restrict__ fc1_bf,
    const float* __restrict__ fc1_b, const u16* __restrict__ fc2_bf,
    const float* __restrict__ fc2_b, const float* __restrict__ n2g,
    const float* __restrict__ n2b)
{
  __shared__ __align__(16) u16 xt[64*200];
  __shared__ __align__(16) u16 hl[64*200];
  __shared__ float lnred[64*8];

  const int tid  = threadIdx.x;
  const int wave = tid >> 6, lane = tid & 63;
  const int kg   = lane >> 4, l15 = lane & 15;
  const size_t t0 = (size_t)blockIdx.x * 64;

  for (int s = tid; s < 64*96; s += 256){
    int t = s / 96, c2 = s - t*96;
    float2 v = LDF2(xio + (t0 + t)*192 + c2*2);
    ST_U32(xt + t*200 + c2*2, pack2(v.x, v.y));
  }
  f32x4 m2[4][3];
  #pragma unroll
  for (int mt = 0; mt < 4; ++mt)
    #pragma unroll
    for (int nt = 0; nt < 3; ++nt){
      float bv = fc2_b[wave*48 + nt*16 + l15];
      m2[mt][nt] = {bv, bv, bv, bv};
    }
  __syncthreads();

  #pragma unroll 1
  for (int c = 0; c < 4; ++c){
    // ---- fc1: h_chunk[:, wave*48 .. +48) ----
    f32x4 a1[4][3];
    #pragma unroll
    for (int mt = 0; mt < 4; ++mt)
      #pragma unroll
      for (int nt = 0; nt < 3; ++nt){
        float bv = fc1_b[c*192 + wave*48 + nt*16 + l15];
        a1[mt][nt] = {bv, bv, bv, bv};
      }
    #pragma unroll 2
    for (int kt = 0; kt < 6; ++kt){
      bf16x8 af[4];
      #pragma unroll
      for (int mt = 0; mt < 4; ++mt)
        af[mt] = ldsfrag(xt + (mt*16 + l15)*200 + kt*32 + kg*8);
      #pragma unroll
      for (int nt = 0; nt < 3; ++nt){
        bf16x8 bfr = gfrag(fc1_bf + (size_t)(c*192 + wave*48 + nt*16 + l15)*192 + kt*32 + kg*8);
        #pragma unroll
        for (int mt = 0; mt < 4; ++mt)
          a1[mt][nt] = MFMA16(af[mt], bfr, a1[mt][nt]);
      }
    }
    #pragma unroll
    for (int mt = 0; mt < 4; ++mt)
      #pragma unroll
      for (int nt = 0; nt < 3; ++nt)
        #pragma unroll
        for (int r = 0; r < 4; ++r)
          hl[(mt*16 + kg*4 + r)*200 + wave*48 + nt*16 + l15] = f2bf(gelu_f(a1[mt][nt][r]));
    __syncthreads();

    // ---- fc2 partial over this chunk (K=192) ----
    #pragma unroll 2
    for (int kt = 0; kt < 6; ++kt){
      bf16x8 af[4];
      #pragma unroll
      for (int mt = 0; mt < 4; ++mt)
        af[mt] = ldsfrag(hl + (mt*16 + l15)*200 + kt*32 + kg*8);
      #pragma unroll
      for (int nt = 0; nt < 3; ++nt){
        bf16x8 bfr = gfrag(fc2_bf + (size_t)(wave*48 + nt*16 + l15)*768 + c*192 + kt*32 + kg*8);
        #pragma unroll
        for (int mt = 0; mt < 4; ++mt)
          m2[mt][nt] = MFMA16(af[mt], bfr, m2[mt][nt]);
      }
    }
    __syncthreads();
  }

  // ---- LN2 + residual (in-place; element-disjoint RMW) ----
  float gv[3], bv2[3];
  #pragma unroll
  for (int nt = 0; nt < 3; ++nt){
    int cc = wave*48 + nt*16 + l15;
    gv[nt] = n2g[cc]; bv2[nt] = n2b[cc];
  }
  #pragma unroll
  for (int mt = 0; mt < 4; ++mt)
    #pragma unroll
    for (int r = 0; r < 4; ++r){
      float s1 = m2[mt][0][r] + m2[mt][1][r] + m2[mt][2][r];
      float s2 = m2[mt][0][r]*m2[mt][0][r] + m2[mt][1][r]*m2[mt][1][r] + m2[mt][2][r]*m2[mt][2][r];
      #pragma unroll
      for (int mk = 1; mk < 16; mk <<= 1){ s1 += __shfl_xor(s1, mk); s2 += __shfl_xor(s2, mk); }
      if (l15 == 0){
        int t = mt*16 + kg*4 + r;
        lnred[t*8 + wave*2]     = s1;
        lnred[t*8 + wave*2 + 1] = s2;
      }
    }
  __syncthreads();
  #pragma unroll
  for (int mt = 0; mt < 4; ++mt)
    #pragma unroll 1
    for (int r = 0; r < 4; ++r){
      int t = mt*16 + kg*4 + r;
      float a1s = lnred[t*8+0] + lnred[t*8+2] + lnred[t*8+4] + lnred[t*8+6];
      float a2s = lnred[t*8+1] + lnred[t*8+3] + lnred[t*8+5] + lnred[t*8+7];
      float mu = a1s * (1.f/192.f);
      float rs = rsqrtf(a2s * (1.f/192.f) - mu*mu + LN_EPS);
      size_t base = (t0 + t)*192;
      #pragma unroll
      for (int nt = 0; nt < 3; ++nt){
        int cc = wave*48 + nt*16 + l15;
        xio[base + cc] = xio[base + cc] + (m2[mt][nt][r] - mu)*rs*gv[nt] + bv2[nt];
      }
    }
}

extern "C" void kernel_launch(void* const* d_in, const int* in_sizes, int n_in,
                              void* d_out, int out_size, void* d_ws, size_t ws_size,
                              hipStream_t stream)
{
  const float* x      = (const float*)d_in[0];
  const float* mask   = (const float*)d_in[1];
  const int*   relidx = (const int*)d_in[2];
  const float* qkv_w  = (const float*)d_in[3];
  const float* qkv_b  = (const float*)d_in[4];
  const float* proj_w = (const float*)d_in[5];
  const float* proj_b = (const float*)d_in[6];
  const float* rpb    = (const float*)d_in[7];
  const float* n1g    = (const float*)d_in[8];
  const float* n1b    = (const float*)d_in[9];
  const float* n2g    = (const float*)d_in[10];
  const float* n2b    = (const float*)d_in[11];
  const float* fc1_w  = (const float*)d_in[12];
  const float* fc1_b  = (const float*)d_in[13];
  const float* fc2_w  = (const float*)d_in[14];
  const float* fc2_b  = (const float*)d_in[15];
  float* xio = (float*)d_out;

  // ws layout: bf16 weights (884736 B) + rpbm f32 (98304 B) = 983040 B
  u16* qkv_bf  = (u16*)d_ws;
  u16* proj_bf = qkv_bf + NQKV;
  u16* fc1_bf  = proj_bf + NPRJ;
  u16* fc2_bf  = fc1_bf + NFC;
  float* rpbm  = (float*)(fc2_bf + NFC);

  k_prep<<<dim3(512), dim3(256), 0, stream>>>(qkv_w, proj_w, fc1_w, fc2_w,
      rpb, relidx, qkv_bf, proj_bf, fc1_bf, fc2_bf, rpbm);
  k_attn<<<dim3(4096), dim3(256), 0, stream>>>(x, mask, rpbm, qkv_bf, qkv_b,
      proj_bf, proj_b, n1g, n1b, xio);
  k_mlp<<<dim3(4096), dim3(256), 0, stream>>>(xio, fc1_bf, fc1_b, fc2_bf, fc2_b,
      n2g, n2b);
}

// Round 5
// 940.191 us; speedup vs baseline: 6.1668x; 1.1034x over previous
//
#include <hip/hip_runtime.h>
#include <hip/hip_bf16.h>
#include <math.h>

typedef unsigned short u16;
typedef unsigned int   u32;
typedef __attribute__((ext_vector_type(8))) short bf16x8;   // 8 bf16 = 4 VGPR
typedef __attribute__((ext_vector_type(4))) float f32x4;

__device__ __forceinline__ u16 f2bf(float f){
  u32 u = __float_as_uint(f);
  u += 0x7fffu + ((u>>16)&1u);          // RNE; inputs never NaN
  return (u16)(u>>16);
}
__device__ __forceinline__ u32 pack2(float a, float b){
  return (u32)f2bf(a) | ((u32)f2bf(b)<<16);
}
__device__ __forceinline__ float2 LDF2(const float* p){ return *(const float2*)p; }
__device__ __forceinline__ float gelu_f(float v){
  float t = __expf(1.5957691216057308f * fmaf(0.044715f*v, v*v, v));
  return v - v/(t + 1.0f);
}

#define ST_U32(p,v) (*(u32*)(p) = (v))
#define MFMA16(a,b,c) __builtin_amdgcn_mfma_f32_16x16x32_bf16((a),(b),(c),0,0,0)

__device__ __forceinline__ bf16x8 ldsfrag(const u16* p){ return *(const bf16x8*)p; }
__device__ __forceinline__ bf16x8 gfrag(const u16* p){ return *(const bf16x8*)p; }

constexpr float SCALE_Q = 0.17677669529663687f;  // 32^-0.5
constexpr float LN_EPS  = 1e-5f;

// ws element counts (u16)
#define NQKV 110592
#define NPRJ 36864
#define NFC  147456
#define QKV_SLAB 50331648ull        // 4096*64*192 u16 per Q/K/VT slab
#define WS_WEIGHTS_B 884736ull
#define WS_RPBM_B    98304ull
#define WS_SPLIT_HDR (WS_WEIGHTS_B + 2*WS_RPBM_B)   // 1081344
#define WS_SPLIT_NEED (WS_SPLIT_HDR + 3ull*QKV_SLAB*2ull)

// =====================================================================
// K0: weight f32->bf16 conversion + rpb gather (row-major, + transposed if mode)
// =====================================================================
__global__ void k_prep(const float* __restrict__ qkv_w, const float* __restrict__ proj_w,
                       const float* __restrict__ fc1_w, const float* __restrict__ fc2_w,
                       const float* __restrict__ rpb, const int* __restrict__ relidx,
                       u16* __restrict__ qkv_bf, u16* __restrict__ proj_bf,
                       u16* __restrict__ fc1_bf, u16* __restrict__ fc2_bf,
                       float* __restrict__ rpbm, float* __restrict__ rpbmT, int mode)
{
  int stride = gridDim.x * blockDim.x;
  int t = blockIdx.x * blockDim.x + threadIdx.x;
  for (int i = t; i < NQKV; i += stride) qkv_bf[i] = f2bf(qkv_w[i]);
  for (int i = t; i < NPRJ; i += stride) proj_bf[i] = f2bf(proj_w[i]);
  for (int i = t; i < NFC;  i += stride) fc1_bf[i]  = f2bf(fc1_w[i]);
  for (int i = t; i < NFC;  i += stride) fc2_bf[i]  = f2bf(fc2_w[i]);
  for (int i = t; i < 6*4096; i += stride){
    int h = i >> 12, ij = i & 4095;
    rpbm[i] = rpb[relidx[ij]*6 + h];
  }
  if (mode){
    for (int i = t; i < 6*4096; i += stride){
      int h = i >> 12, ij = i & 4095;           // ij = col*64 + row (transposed)
      int col = ij >> 6, row = ij & 63;
      rpbmT[i] = rpb[relidx[row*64 + col]*6 + h];
    }
  }
}

// =====================================================================
// K1a (split path): per-window qkv GEMM -> Qg (scaled), Kg, VTg (transposed)
// block = window, 4 waves; 1 barrier
// =====================================================================
__global__ __launch_bounds__(256, 4) void k_qkv(
    const float* __restrict__ x, const u16* __restrict__ qkv_bf,
    const float* __restrict__ qkv_b,
    u16* __restrict__ Qg, u16* __restrict__ Kg, u16* __restrict__ VTg)
{
  __shared__ __align__(16) u16 xw[64*200];
  const int tid = threadIdx.x, wave = tid >> 6, lane = tid & 63;
  const int kg = lane >> 4, l15 = lane & 15;
  const int wi = blockIdx.x, b = wi >> 10, wm = wi & 1023;
  const int wh = wm >> 5, ww = wm & 31;
  const size_t imgbase = (size_t)b * (256*256*192);

  for (int s = tid; s < 64*96; s += 256){
    int t = s / 96, c2 = s - t*96;
    int i = t >> 3, j = t & 7;
    int h0 = ((wh<<3) + i + 4) & 255;
    int w0 = ((ww<<3) + j + 4) & 255;
    float2 v = LDF2(x + imgbase + (size_t)(h0*256 + w0)*192 + c2*2);
    ST_U32(xw + t*200 + c2*2, pack2(v.x, v.y));
  }
  __syncthreads();

  const size_t wbase = (size_t)wi * 12288;
  #pragma unroll 1
  for (int batch = 0; batch < 3; ++batch){
    const int col0 = wave*144 + batch*48;
    f32x4 a[4][3];
    #pragma unroll
    for (int j = 0; j < 3; ++j){
      float bv = qkv_b[col0 + j*16 + l15];
      #pragma unroll
      for (int mt = 0; mt < 4; ++mt) a[mt][j] = {bv, bv, bv, bv};
    }
    #pragma unroll 2
    for (int kt = 0; kt < 6; ++kt){
      bf16x8 af[4];
      #pragma unroll
      for (int mt = 0; mt < 4; ++mt)
        af[mt] = ldsfrag(xw + (mt*16 + l15)*200 + kt*32 + kg*8);
      #pragma unroll
      for (int j = 0; j < 3; ++j){
        bf16x8 bfr = gfrag(qkv_bf + (col0 + j*16 + l15)*192 + kt*32 + kg*8);
        #pragma unroll
        for (int mt = 0; mt < 4; ++mt)
          a[mt][j] = MFMA16(af[mt], bfr, a[mt][j]);
      }
    }
    #pragma unroll
    for (int j = 0; j < 3; ++j){
      int colg = col0 + j*16 + l15;          // uniform section per (wave,batch,j)
      if (colg < 192){
        #pragma unroll
        for (int mt = 0; mt < 4; ++mt)
          #pragma unroll
          for (int r = 0; r < 4; ++r)
            Qg[wbase + (size_t)(mt*16 + kg*4 + r)*192 + colg] = f2bf(a[mt][j][r]*SCALE_Q);
      } else if (colg < 384){
        #pragma unroll
        for (int mt = 0; mt < 4; ++mt)
          #pragma unroll
          for (int r = 0; r < 4; ++r)
            Kg[wbase + (size_t)(mt*16 + kg*4 + r)*192 + (colg - 192)] = f2bf(a[mt][j][r]);
      } else {
        #pragma unroll
        for (int mt = 0; mt < 4; ++mt){
          ushort4 pk = { f2bf(a[mt][j][0]), f2bf(a[mt][j][1]),
                         f2bf(a[mt][j][2]), f2bf(a[mt][j][3]) };
          *(ushort4*)(VTg + wbase + (size_t)(colg - 384)*64 + mt*16 + kg*4) = pk;
        }
      }
    }
  }
}

// =====================================================================
// K1b (split path): attention core + proj + LN1 + residual -> x1
// block = window, 4 waves (wave = 16 query rows); 3 barriers total
// =====================================================================
__global__ __launch_bounds__(256, 4) void k_attn2(
    const float* __restrict__ x, const float* __restrict__ mask,
    const float* __restrict__ rpbmT,
    const u16* __restrict__ Qg, const u16* __restrict__ Kg,
    const u16* __restrict__ VTg,
    const u16* __restrict__ proj_bf, const float* __restrict__ proj_b,
    const float* __restrict__ n1g, const float* __restrict__ n1b,
    float* __restrict__ x1)
{
  __shared__ __align__(16) u16 prb[64*72];
  __shared__ __align__(16) u16 obuf[64*200];
  __shared__ float lnred[64*8];

  const int tid = threadIdx.x, wave = tid >> 6, lane = tid & 63;
  const int kg = lane >> 4, l15 = lane & 15;
  const int wi = blockIdx.x, b = wi >> 10, wm = wi & 1023;
  const int wh = wm >> 5, ww = wm & 31;
  const size_t imgbase = (size_t)b * (256*256*192);
  const size_t wbase = (size_t)wi * 12288;

  f32x4 pj[4][3];
  #pragma unroll
  for (int mt = 0; mt < 4; ++mt)
    #pragma unroll
    for (int nt = 0; nt < 3; ++nt){
      float bv = proj_b[wave*48 + nt*16 + l15];
      pj[mt][nt] = {bv, bv, bv, bv};
    }

  #pragma unroll 1
  for (int h = 0; h < 6; ++h){
    const f32x4 z = {0.f, 0.f, 0.f, 0.f};
    // ---- QK^T: A,B frags straight from global ----
    bf16x8 qf = gfrag(Qg + wbase + (size_t)(wave*16 + l15)*192 + h*32 + kg*8);
    f32x4 at[4];
    #pragma unroll
    for (int nt = 0; nt < 4; ++nt){
      bf16x8 kf = gfrag(Kg + wbase + (size_t)(nt*16 + l15)*192 + h*32 + kg*8);
      at[nt] = MFMA16(qf, kf, z);
    }
    // ---- + rpb^T + mask (symmetric -> transposed load is direct) ----
    {
      const float* rb = rpbmT + h*4096;
      const float* mb = mask + (size_t)wm*4096;
      #pragma unroll
      for (int nt = 0; nt < 4; ++nt){
        int cidx = (nt*16 + l15)*64 + wave*16 + kg*4;
        float4 r4 = *(const float4*)(rb + cidx);
        float4 m4 = *(const float4*)(mb + cidx);
        at[nt][0] += r4.x + m4.x;
        at[nt][1] += r4.y + m4.y;
        at[nt][2] += r4.z + m4.z;
        at[nt][3] += r4.w + m4.w;
      }
    }
    // ---- softmax (16-lane group) ----
    #pragma unroll
    for (int r = 0; r < 4; ++r){
      float m0 = fmaxf(fmaxf(at[0][r], at[1][r]), fmaxf(at[2][r], at[3][r]));
      #pragma unroll
      for (int mk = 1; mk < 16; mk <<= 1) m0 = fmaxf(m0, __shfl_xor(m0, mk));
      float s = 0.f;
      #pragma unroll
      for (int nt = 0; nt < 4; ++nt){ at[nt][r] = __expf(at[nt][r] - m0); s += at[nt][r]; }
      #pragma unroll
      for (int mk = 1; mk < 16; mk <<= 1) s += __shfl_xor(s, mk);
      float inv = 1.0f / s;
      #pragma unroll
      for (int nt = 0; nt < 4; ++nt) at[nt][r] *= inv;
    }
    // ---- P -> LDS (wave-local rows; no barrier needed) ----
    #pragma unroll
    for (int nt = 0; nt < 4; ++nt)
      #pragma unroll
      for (int r = 0; r < 4; ++r)
        prb[(wave*16 + kg*4 + r)*72 + nt*16 + l15] = f2bf(at[nt][r]);
    // ---- PV: P from LDS (transposed), V^T from global ----
    {
      f32x4 ov[2] = {z, z};
      #pragma unroll
      for (int kt = 0; kt < 2; ++kt){
        bf16x8 pf = ldsfrag(prb + (wave*16 + l15)*72 + kt*32 + kg*8);
        #pragma unroll
        for (int d = 0; d < 2; ++d){
          bf16x8 vf = gfrag(VTg + wbase + (size_t)(h*32 + d*16 + l15)*64 + kt*32 + kg*8);
          ov[d] = MFMA16(pf, vf, ov[d]);
        }
      }
      #pragma unroll
      for (int d = 0; d < 2; ++d)
        #pragma unroll
        for (int r = 0; r < 4; ++r)
          obuf[(wave*16 + kg*4 + r)*200 + h*32 + d*16 + l15] = f2bf(ov[d][r]);
    }
  }
  __syncthreads();

  // ---- proj: wave owns out cols [wave*48,+48), K=192 ----
  #pragma unroll 2
  for (int kt = 0; kt < 6; ++kt){
    bf16x8 af[4];
    #pragma unroll
    for (int mt = 0; mt < 4; ++mt)
      af[mt] = ldsfrag(obuf + (mt*16 + l15)*200 + kt*32 + kg*8);
    #pragma unroll
    for (int nt = 0; nt < 3; ++nt){
      bf16x8 bfr = gfrag(proj_bf + (wave*48 + nt*16 + l15)*192 + kt*32 + kg*8);
      #pragma unroll
      for (int mt = 0; mt < 4; ++mt)
        pj[mt][nt] = MFMA16(af[mt], bfr, pj[mt][nt]);
    }
  }

  // ---- LN1 + residual, scatter to un-shifted coords ----
  float gv[3], bv2[3];
  #pragma unroll
  for (int nt = 0; nt < 3; ++nt){
    int c = wave*48 + nt*16 + l15;
    gv[nt] = n1g[c]; bv2[nt] = n1b[c];
  }
  #pragma unroll
  for (int mt = 0; mt < 4; ++mt)
    #pragma unroll
    for (int r = 0; r < 4; ++r){
      float s1 = pj[mt][0][r] + pj[mt][1][r] + pj[mt][2][r];
      float s2 = pj[mt][0][r]*pj[mt][0][r] + pj[mt][1][r]*pj[mt][1][r] + pj[mt][2][r]*pj[mt][2][r];
      #pragma unroll
      for (int mk = 1; mk < 16; mk <<= 1){ s1 += __shfl_xor(s1, mk); s2 += __shfl_xor(s2, mk); }
      if (l15 == 0){
        int t = mt*16 + kg*4 + r;
        lnred[t*8 + wave*2]     = s1;
        lnred[t*8 + wave*2 + 1] = s2;
      }
    }
  __syncthreads();
  #pragma unroll
  for (int mt = 0; mt < 4; ++mt)
    #pragma unroll 1
    for (int r = 0; r < 4; ++r){
      int t = mt*16 + kg*4 + r;
      float a1 = lnred[t*8+0] + lnred[t*8+2] + lnred[t*8+4] + lnred[t*8+6];
      float a2 = lnred[t*8+1] + lnred[t*8+3] + lnred[t*8+5] + lnred[t*8+7];
      float mu = a1 * (1.f/192.f);
      float rs = rsqrtf(a2 * (1.f/192.f) - mu*mu + LN_EPS);
      int i = t >> 3, j = t & 7;
      int h0 = ((wh<<3) + i + 4) & 255, w0 = ((ww<<3) + j + 4) & 255;
      size_t base = imgbase + (size_t)(h0*256 + w0)*192;
      #pragma unroll
      for (int nt = 0; nt < 3; ++nt){
        int c = wave*48 + nt*16 + l15;
        x1[base + c] = x[base + c] + (pj[mt][nt][r] - mu)*rs*gv[nt] + bv2[nt];
      }
    }
}

// =====================================================================
// K1 (fallback, round-4 proven): monolithic attention
// =====================================================================
__global__ __launch_bounds__(256, 3) void k_attn(
    const float* __restrict__ x, const float* __restrict__ mask,
    const float* __restrict__ rpbm, const u16* __restrict__ qkv_bf,
    const float* __restrict__ qkv_b, const u16* __restrict__ proj_bf,
    const float* __restrict__ proj_b, const float* __restrict__ n1g,
    const float* __restrict__ n1b, float* __restrict__ x1)
{
  __shared__ __align__(16) u16 xw[64*200];
  __shared__ __align__(16) u16 qkvh[64*72];
  __shared__ __align__(16) u16 vT[32*72];
  __shared__ __align__(16) u16 prb[64*72];
  __shared__ __align__(16) u16 outh[64*40];
  float* lnred = (float*)outh;

  const int tid  = threadIdx.x;
  const int wave = tid >> 6, lane = tid & 63;
  const int kg   = lane >> 4, l15 = lane & 15;
  const int wi = blockIdx.x;
  const int b  = wi >> 10, wm = wi & 1023;
  const int wh = wm >> 5,  ww = wm & 31;
  const size_t imgbase = (size_t)b * (256*256*192);

  for (int s = tid; s < 64*96; s += 256){
    int t = s / 96, c2 = s - t*96;
    int i = t >> 3, j = t & 7;
    int h0 = ((wh<<3) + i + 4) & 255;
    int w0 = ((ww<<3) + j + 4) & 255;
    float2 v = LDF2(x + imgbase + (size_t)(h0*256 + w0)*192 + c2*2);
    ST_U32(xw + t*200 + c2*2, pack2(v.x, v.y));
  }

  f32x4 pj[4][3];
  #pragma unroll
  for (int mt = 0; mt < 4; ++mt)
    #pragma unroll
    for (int nt = 0; nt < 3; ++nt){
      float bv = proj_b[wave*48 + nt*16 + l15];
      pj[mt][nt] = {bv, bv, bv, bv};
    }
  __syncthreads();

  #pragma unroll 1
  for (int h = 0; h < 6; ++h){
    f32x4 qa[6];
    #pragma unroll
    for (int nt = 0; nt < 6; ++nt){
      float bv = qkv_b[(nt>>1)*192 + h*32 + (nt&1)*16 + l15];
      qa[nt] = {bv, bv, bv, bv};
    }
    #pragma unroll 2
    for (int kt = 0; kt < 6; ++kt){
      bf16x8 af = ldsfrag(xw + (wave*16 + l15)*200 + kt*32 + kg*8);
      #pragma unroll
      for (int nt = 0; nt < 6; ++nt){
        bf16x8 bfr = gfrag(qkv_bf + ((nt>>1)*192 + h*32 + (nt&1)*16 + l15)*192 + kt*32 + kg*8);
        qa[nt] = MFMA16(af, bfr, qa[nt]);
      }
    }
    #pragma unroll
    for (int nt = 0; nt < 2; ++nt)
      #pragma unroll
      for (int r = 0; r < 4; ++r)
        qkvh[(wave*16 + kg*4 + r)*72 + nt*16 + l15] = f2bf(qa[nt][r]*SCALE_Q);
    #pragma unroll
    for (int nt = 2; nt < 4; ++nt)
      #pragma unroll
      for (int r = 0; r < 4; ++r)
        qkvh[(wave*16 + kg*4 + r)*72 + 32 + (nt-2)*16 + l15] = f2bf(qa[nt][r]);
    #pragma unroll
    for (int nt = 4; nt < 6; ++nt)
      #pragma unroll
      for (int r = 0; r < 4; ++r)
        vT[((nt-4)*16 + l15)*72 + wave*16 + kg*4 + r] = f2bf(qa[nt][r]);
    __syncthreads();

    f32x4 at[4];
    {
      const f32x4 z = {0.f, 0.f, 0.f, 0.f};
      bf16x8 qf = ldsfrag(qkvh + (wave*16 + l15)*72 + kg*8);
      #pragma unroll
      for (int nt = 0; nt < 4; ++nt){
        bf16x8 kf = ldsfrag(qkvh + (nt*16 + l15)*72 + 32 + kg*8);
        at[nt] = MFMA16(qf, kf, z);
      }
    }
    {
      const float* rb = rpbm + h*4096;
      const float* mb = mask + (size_t)wm*4096;
      #pragma unroll
      for (int nt = 0; nt < 4; ++nt)
        #pragma unroll
        for (int r = 0; r < 4; ++r){
          int idx = (wave*16 + kg*4 + r)*64 + nt*16 + l15;
          at[nt][r] += rb[idx] + mb[idx];
        }
    }
    #pragma unroll
    for (int r = 0; r < 4; ++r){
      float m0 = fmaxf(fmaxf(at[0][r], at[1][r]), fmaxf(at[2][r], at[3][r]));
      #pragma unroll
      for (int mk = 1; mk < 16; mk <<= 1) m0 = fmaxf(m0, __shfl_xor(m0, mk));
      float s = 0.f;
      #pragma unroll
      for (int nt = 0; nt < 4; ++nt){ at[nt][r] = __expf(at[nt][r] - m0); s += at[nt][r]; }
      #pragma unroll
      for (int mk = 1; mk < 16; mk <<= 1) s += __shfl_xor(s, mk);
      float inv = 1.0f / s;
      #pragma unroll
      for (int nt = 0; nt < 4; ++nt) at[nt][r] *= inv;
    }
    #pragma unroll
    for (int nt = 0; nt < 4; ++nt)
      #pragma unroll
      for (int r = 0; r < 4; ++r)
        prb[(wave*16 + kg*4 + r)*72 + nt*16 + l15] = f2bf(at[nt][r]);

    {
      f32x4 ov[2] = {{0,0,0,0},{0,0,0,0}};
      #pragma unroll
      for (int kt = 0; kt < 2; ++kt){
        bf16x8 pf = ldsfrag(prb + (wave*16 + l15)*72 + kt*32 + kg*8);
        #pragma unroll
        for (int nt = 0; nt < 2; ++nt){
          bf16x8 vf = ldsfrag(vT + (nt*16 + l15)*72 + kt*32 + kg*8);
          ov[nt] = MFMA16(pf, vf, ov[nt]);
        }
      }
      #pragma unroll
      for (int nt = 0; nt < 2; ++nt)
        #pragma unroll
        for (int r = 0; r < 4; ++r)
          outh[(wave*16 + kg*4 + r)*40 + nt*16 + l15] = f2bf(ov[nt][r]);
    }
    __syncthreads();

    {
      bf16x8 pw[3];
      #pragma unroll
      for (int nt = 0; nt < 3; ++nt)
        pw[nt] = gfrag(proj_bf + (wave*48 + nt*16 + l15)*192 + h*32 + kg*8);
      #pragma unroll
      for (int mt = 0; mt < 4; ++mt){
        bf16x8 af = ldsfrag(outh + (mt*16 + l15)*40 + kg*8);
        #pragma unroll
        for (int nt = 0; nt < 3; ++nt)
          pj[mt][nt] = MFMA16(af, pw[nt], pj[mt][nt]);
      }
    }
    __syncthreads();
  }

  float gv[3], bv2[3];
  #pragma unroll
  for (int nt = 0; nt < 3; ++nt){
    int c = wave*48 + nt*16 + l15;
    gv[nt] = n1g[c]; bv2[nt] = n1b[c];
  }
  #pragma unroll
  for (int mt = 0; mt < 4; ++mt)
    #pragma unroll
    for (int r = 0; r < 4; ++r){
      float s1 = pj[mt][0][r] + pj[mt][1][r] + pj[mt][2][r];
      float s2 = pj[mt][0][r]*pj[mt][0][r] + pj[mt][1][r]*pj[mt][1][r] + pj[mt][2][r]*pj[mt][2][r];
      #pragma unroll
      for (int mk = 1; mk < 16; mk <<= 1){ s1 += __shfl_xor(s1, mk); s2 += __shfl_xor(s2, mk); }
      if (l15 == 0){
        int t = mt*16 + kg*4 + r;
        lnred[t*8 + wave*2]     = s1;
        lnred[t*8 + wave*2 + 1] = s2;
      }
    }
  __syncthreads();
  #pragma unroll
  for (int mt = 0; mt < 4; ++mt)
    #pragma unroll 1
    for (int r = 0; r < 4; ++r){
      int t = mt*16 + kg*4 + r;
      float a1 = lnred[t*8+0] + lnred[t*8+2] + lnred[t*8+4] + lnred[t*8+6];
      float a2 = lnred[t*8+1] + lnred[t*8+3] + lnred[t*8+5] + lnred[t*8+7];
      float mu = a1 * (1.f/192.f);
      float rs = rsqrtf(a2 * (1.f/192.f) - mu*mu + LN_EPS);
      int i = t >> 3, j = t & 7;
      int h0 = ((wh<<3) + i + 4) & 255, w0 = ((ww<<3) + j + 4) & 255;
      size_t base = imgbase + (size_t)(h0*256 + w0)*192;
      #pragma unroll
      for (int nt = 0; nt < 3; ++nt){
        int c = wave*48 + nt*16 + l15;
        x1[base + c] = x[base + c] + (pj[mt][nt][r] - mu)*rs*gv[nt] + bv2[nt];
      }
    }
}

// =====================================================================
// K2: MLP (fc1 + GELU + fc2) + LN2 + residual, IN-PLACE on xio (f32)
// =====================================================================
__global__ __launch_bounds__(256, 3) void k_mlp(
    float* xio, const u16* __restrict__ fc1_bf,
    const float* __restrict__ fc1_b, const u16* __restrict__ fc2_bf,
    const float* __restrict__ fc2_b, const float* __restrict__ n2g,
    const float* __restrict__ n2b)
{
  __shared__ __align__(16) u16 xt[64*200];
  __shared__ __align__(16) u16 hl[64*200];
  __shared__ float lnred[64*8];

  const int tid  = threadIdx.x;
  const int wave = tid >> 6, lane = tid & 63;
  const int kg   = lane >> 4, l15 = lane & 15;
  const size_t t0 = (size_t)blockIdx.x * 64;

  for (int s = tid; s < 64*96; s += 256){
    int t = s / 96, c2 = s - t*96;
    float2 v = LDF2(xio + (t0 + t)*192 + c2*2);
    ST_U32(xt + t*200 + c2*2, pack2(v.x, v.y));
  }
  f32x4 m2[4][3];
  #pragma unroll
  for (int mt = 0; mt < 4; ++mt)
    #pragma unroll
    for (int nt = 0; nt < 3; ++nt){
      float bv = fc2_b[wave*48 + nt*16 + l15];
      m2[mt][nt] = {bv, bv, bv, bv};
    }
  __syncthreads();

  #pragma unroll 1
  for (int c = 0; c < 4; ++c){
    f32x4 a1[4][3];
    #pragma unroll
    for (int mt = 0; mt < 4; ++mt)
      #pragma unroll
      for (int nt = 0; nt < 3; ++nt){
        float bv = fc1_b[c*192 + wave*48 + nt*16 + l15];
        a1[mt][nt] = {bv, bv, bv, bv};
      }
    #pragma unroll 2
    for (int kt = 0; kt < 6; ++kt){
      bf16x8 af[4];
      #pragma unroll
      for (int mt = 0; mt < 4; ++mt)
        af[mt] = ldsfrag(xt + (mt*16 + l15)*200 + kt*32 + kg*8);
      #pragma unroll
      for (int nt = 0; nt < 3; ++nt){
        bf16x8 bfr = gfrag(fc1_bf + (size_t)(c*192 + wave*48 + nt*16 + l15)*192 + kt*32 + kg*8);
        #pragma unroll
        for (int mt = 0; mt < 4; ++mt)
          a1[mt][nt] = MFMA16(af[mt], bfr, a1[mt][nt]);
      }
    }
    #pragma unroll
    for (int mt = 0; mt < 4; ++mt)
      #pragma unroll
      for (int nt = 0; nt < 3; ++nt)
        #pragma unroll
        for (int r = 0; r < 4; ++r)
          hl[(mt*16 + kg*4 + r)*200 + wave*48 + nt*16 + l15] = f2bf(gelu_f(a1[mt][nt][r]));
    __syncthreads();

    #pragma unroll 2
    for (int kt = 0; kt < 6; ++kt){
      bf16x8 af[4];
      #pragma unroll
      for (int mt = 0; mt < 4; ++mt)
        af[mt] = ldsfrag(hl + (mt*16 + l15)*200 + kt*32 + kg*8);
      #pragma unroll
      for (int nt = 0; nt < 3; ++nt){
        bf16x8 bfr = gfrag(fc2_bf + (size_t)(wave*48 + nt*16 + l15)*768 + c*192 + kt*32 + kg*8);
        #pragma unroll
        for (int mt = 0; mt < 4; ++mt)
          m2[mt][nt] = MFMA16(af[mt], bfr, m2[mt][nt]);
      }
    }
    __syncthreads();
  }

  float gv[3], bv2[3];
  #pragma unroll
  for (int nt = 0; nt < 3; ++nt){
    int cc = wave*48 + nt*16 + l15;
    gv[nt] = n2g[cc]; bv2[nt] = n2b[cc];
  }
  #pragma unroll
  for (int mt = 0; mt < 4; ++mt)
    #pragma unroll
    for (int r = 0; r < 4; ++r){
      float s1 = m2[mt][0][r] + m2[mt][1][r] + m2[mt][2][r];
      float s2 = m2[mt][0][r]*m2[mt][0][r] + m2[mt][1][r]*m2[mt][1][r] + m2[mt][2][r]*m2[mt][2][r];
      #pragma unroll
      for (int mk = 1; mk < 16; mk <<= 1){ s1 += __shfl_xor(s1, mk); s2 += __shfl_xor(s2, mk); }
      if (l15 == 0){
        int t = mt*16 + kg*4 + r;
        lnred[t*8 + wave*2]     = s1;
        lnred[t*8 + wave*2 + 1] = s2;
      }
    }
  __syncthreads();
  #pragma unroll
  for (int mt = 0; mt < 4; ++mt)
    #pragma unroll 1
    for (int r = 0; r < 4; ++r){
      int t = mt*16 + kg*4 + r;
      float a1s = lnred[t*8+0] + lnred[t*8+2] + lnred[t*8+4] + lnred[t*8+6];
      float a2s = lnred[t*8+1] + lnred[t*8+3] + lnred[t*8+5] + lnred[t*8+7];
      float mu = a1s * (1.f/192.f);
      float rs = rsqrtf(a2s * (1.f/192.f) - mu*mu + LN_EPS);
      size_t base = (t0 + t)*192;
      #pragma unroll
      for (int nt = 0; nt < 3; ++nt){
        int cc = wave*48 + nt*16 + l15;
        xio[base + cc] = xio[base + cc] + (m2[mt][nt][r] - mu)*rs*gv[nt] + bv2[nt];
      }
    }
}

extern "C" void kernel_launch(void* const* d_in, const int* in_sizes, int n_in,
                              void* d_out, int out_size, void* d_ws, size_t ws_size,
                              hipStream_t stream)
{
  const float* x      = (const float*)d_in[0];
  const float* mask   = (const float*)d_in[1];
  const int*   relidx = (const int*)d_in[2];
  const float* qkv_w  = (const float*)d_in[3];
  const float* qkv_b  = (const float*)d_in[4];
  const float* proj_w = (const float*)d_in[5];
  const float* proj_b = (const float*)d_in[6];
  const float* rpb    = (const float*)d_in[7];
  const float* n1g    = (const float*)d_in[8];
  const float* n1b    = (const float*)d_in[9];
  const float* n2g    = (const float*)d_in[10];
  const float* n2b    = (const float*)d_in[11];
  const float* fc1_w  = (const float*)d_in[12];
  const float* fc1_b  = (const float*)d_in[13];
  const float* fc2_w  = (const float*)d_in[14];
  const float* fc2_b  = (const float*)d_in[15];
  float* xio = (float*)d_out;

  u16* qkv_bf  = (u16*)d_ws;
  u16* proj_bf = qkv_bf + NQKV;
  u16* fc1_bf  = proj_bf + NPRJ;
  u16* fc2_bf  = fc1_bf + NFC;
  float* rpbm  = (float*)(fc2_bf + NFC);
  float* rpbmT = rpbm + 6*4096;
  u16* Qg = (u16*)((char*)d_ws + WS_SPLIT_HDR);
  u16* Kg = Qg + QKV_SLAB;
  u16* VTg = Kg + QKV_SLAB;

  const int split = (ws_size >= WS_SPLIT_NEED) ? 1 : 0;

  k_prep<<<dim3(512), dim3(256), 0, stream>>>(qkv_w, proj_w, fc1_w, fc2_w,
      rpb, relidx, qkv_bf, proj_bf, fc1_bf, fc2_bf, rpbm, rpbmT, split);
  if (split){
    k_qkv<<<dim3(4096), dim3(256), 0, stream>>>(x, qkv_bf, qkv_b, Qg, Kg, VTg);
    k_attn2<<<dim3(4096), dim3(256), 0, stream>>>(x, mask, rpbmT, Qg, Kg, VTg,
        proj_bf, proj_b, n1g, n1b, xio);
  } else {
    k_attn<<<dim3(4096), dim3(256), 0, stream>>>(x, mask, rpbm, qkv_bf, qkv_b,
        proj_bf, proj_b, n1g, n1b, xio);
  }
  k_mlp<<<dim3(4096), dim3(256), 0, stream>>>(xio, fc1_bf, fc1_b, fc2_bf, fc2_b,
      n2g, n2b);
}

// Round 6
// 939.717 us; speedup vs baseline: 6.1699x; 1.0005x over previous
//
#include <hip/hip_runtime.h>
#include <hip/hip_bf16.h>
#include <math.h>

typedef unsigned short u16;
typedef unsigned int   u32;
typedef __attribute__((ext_vector_type(8))) short bf16x8;   // 8 bf16 = 4 VGPR
typedef __attribute__((ext_vector_type(4))) float f32x4;

__device__ __forceinline__ u16 f2bf(float f){
  u32 u = __float_as_uint(f);
  u += 0x7fffu + ((u>>16)&1u);          // RNE; inputs never NaN
  return (u16)(u>>16);
}
__device__ __forceinline__ u32 pack2(float a, float b){
  return (u32)f2bf(a) | ((u32)f2bf(b)<<16);
}
__device__ __forceinline__ float2 LDF2(const float* p){ return *(const float2*)p; }
__device__ __forceinline__ float gelu_f(float v){
  float t = __expf(1.5957691216057308f * fmaf(0.044715f*v, v*v, v));
  return v - v/(t + 1.0f);
}

#define ST_U32(p,v) (*(u32*)(p) = (v))
#define MFMA16(a,b,c) __builtin_amdgcn_mfma_f32_16x16x32_bf16((a),(b),(c),0,0,0)

__device__ __forceinline__ bf16x8 ldsfrag(const u16* p){ return *(const bf16x8*)p; }
__device__ __forceinline__ bf16x8 gfrag(const u16* p){ return *(const bf16x8*)p; }

constexpr float SCALE_Q = 0.17677669529663687f;  // 32^-0.5
constexpr float LN_EPS  = 1e-5f;

// ws element counts (u16)
#define NQKV 110592
#define NPRJ 36864
#define NFC  147456
#define QKV_SLAB 50331648ull        // 4096*64*192 u16 per Q/K/VT slab
#define WS_WEIGHTS_B 884736ull
#define WS_RPBM_B    98304ull
#define WS_SPLIT_HDR (WS_WEIGHTS_B + 2*WS_RPBM_B)   // 1081344
#define WS_SPLIT_NEED (WS_SPLIT_HDR + 3ull*QKV_SLAB*2ull)

// =====================================================================
// K0: weight f32->bf16 conversion + rpb gather (row-major, + transposed if mode)
// =====================================================================
__global__ void k_prep(const float* __restrict__ qkv_w, const float* __restrict__ proj_w,
                       const float* __restrict__ fc1_w, const float* __restrict__ fc2_w,
                       const float* __restrict__ rpb, const int* __restrict__ relidx,
                       u16* __restrict__ qkv_bf, u16* __restrict__ proj_bf,
                       u16* __restrict__ fc1_bf, u16* __restrict__ fc2_bf,
                       float* __restrict__ rpbm, float* __restrict__ rpbmT, int mode)
{
  int stride = gridDim.x * blockDim.x;
  int t = blockIdx.x * blockDim.x + threadIdx.x;
  for (int i = t; i < NQKV; i += stride) qkv_bf[i] = f2bf(qkv_w[i]);
  for (int i = t; i < NPRJ; i += stride) proj_bf[i] = f2bf(proj_w[i]);
  for (int i = t; i < NFC;  i += stride) fc1_bf[i]  = f2bf(fc1_w[i]);
  for (int i = t; i < NFC;  i += stride) fc2_bf[i]  = f2bf(fc2_w[i]);
  for (int i = t; i < 6*4096; i += stride){
    int h = i >> 12, ij = i & 4095;
    rpbm[i] = rpb[relidx[ij]*6 + h];
  }
  if (mode){
    for (int i = t; i < 6*4096; i += stride){
      int h = i >> 12, ij = i & 4095;           // ij = col*64 + row (transposed)
      int col = ij >> 6, row = ij & 63;
      rpbmT[i] = rpb[relidx[row*64 + col]*6 + h];
    }
  }
}

// =====================================================================
// K1a (split path): per-window qkv GEMM -> Qg (scaled), Kg, VTg (transposed)
// block = window, 4 waves; 1 barrier
// =====================================================================
__global__ __launch_bounds__(256, 4) void k_qkv(
    const float* __restrict__ x, const u16* __restrict__ qkv_bf,
    const float* __restrict__ qkv_b,
    u16* __restrict__ Qg, u16* __restrict__ Kg, u16* __restrict__ VTg)
{
  __shared__ __align__(16) u16 xw[64*200];
  const int tid = threadIdx.x, wave = tid >> 6, lane = tid & 63;
  const int kg = lane >> 4, l15 = lane & 15;
  const int wi = blockIdx.x, b = wi >> 10, wm = wi & 1023;
  const int wh = wm >> 5, ww = wm & 31;
  const size_t imgbase = (size_t)b * (256*256*192);

  for (int s = tid; s < 64*96; s += 256){
    int t = s / 96, c2 = s - t*96;
    int i = t >> 3, j = t & 7;
    int h0 = ((wh<<3) + i + 4) & 255;
    int w0 = ((ww<<3) + j + 4) & 255;
    float2 v = LDF2(x + imgbase + (size_t)(h0*256 + w0)*192 + c2*2);
    ST_U32(xw + t*200 + c2*2, pack2(v.x, v.y));
  }
  __syncthreads();

  const size_t wbase = (size_t)wi * 12288;
  #pragma unroll 1
  for (int batch = 0; batch < 3; ++batch){
    const int col0 = wave*144 + batch*48;
    f32x4 a[4][3];
    #pragma unroll
    for (int j = 0; j < 3; ++j){
      float bv = qkv_b[col0 + j*16 + l15];
      #pragma unroll
      for (int mt = 0; mt < 4; ++mt) a[mt][j] = {bv, bv, bv, bv};
    }
    #pragma unroll 2
    for (int kt = 0; kt < 6; ++kt){
      bf16x8 af[4];
      #pragma unroll
      for (int mt = 0; mt < 4; ++mt)
        af[mt] = ldsfrag(xw + (mt*16 + l15)*200 + kt*32 + kg*8);
      #pragma unroll
      for (int j = 0; j < 3; ++j){
        bf16x8 bfr = gfrag(qkv_bf + (col0 + j*16 + l15)*192 + kt*32 + kg*8);
        #pragma unroll
        for (int mt = 0; mt < 4; ++mt)
          a[mt][j] = MFMA16(af[mt], bfr, a[mt][j]);
      }
    }
    #pragma unroll
    for (int j = 0; j < 3; ++j){
      int colg = col0 + j*16 + l15;          // uniform section per (wave,batch,j)
      if (colg < 192){
        #pragma unroll
        for (int mt = 0; mt < 4; ++mt)
          #pragma unroll
          for (int r = 0; r < 4; ++r)
            Qg[wbase + (size_t)(mt*16 + kg*4 + r)*192 + colg] = f2bf(a[mt][j][r]*SCALE_Q);
      } else if (colg < 384){
        #pragma unroll
        for (int mt = 0; mt < 4; ++mt)
          #pragma unroll
          for (int r = 0; r < 4; ++r)
            Kg[wbase + (size_t)(mt*16 + kg*4 + r)*192 + (colg - 192)] = f2bf(a[mt][j][r]);
      } else {
        #pragma unroll
        for (int mt = 0; mt < 4; ++mt){
          ushort4 pk = { f2bf(a[mt][j][0]), f2bf(a[mt][j][1]),
                         f2bf(a[mt][j][2]), f2bf(a[mt][j][3]) };
          *(ushort4*)(VTg + wbase + (size_t)(colg - 384)*64 + mt*16 + kg*4) = pk;
        }
      }
    }
  }
}

// =====================================================================
// K1b (split path): attention core + proj + LN1 + residual -> x1
// block = window, 4 waves (wave = 16 query rows); 3 barriers total
// =====================================================================
__global__ __launch_bounds__(256, 4) void k_attn2(
    const float* __restrict__ x, const float* __restrict__ mask,
    const float* __restrict__ rpbmT,
    const u16* __restrict__ Qg, const u16* __restrict__ Kg,
    const u16* __restrict__ VTg,
    const u16* __restrict__ proj_bf, const float* __restrict__ proj_b,
    const float* __restrict__ n1g, const float* __restrict__ n1b,
    float* __restrict__ x1)
{
  __shared__ __align__(16) u16 prb[64*72];
  __shared__ __align__(16) u16 obuf[64*200];
  __shared__ float lnred[64*8];

  const int tid = threadIdx.x, wave = tid >> 6, lane = tid & 63;
  const int kg = lane >> 4, l15 = lane & 15;
  const int wi = blockIdx.x, b = wi >> 10, wm = wi & 1023;
  const int wh = wm >> 5, ww = wm & 31;
  const size_t imgbase = (size_t)b * (256*256*192);
  const size_t wbase = (size_t)wi * 12288;

  f32x4 pj[4][3];
  #pragma unroll
  for (int mt = 0; mt < 4; ++mt)
    #pragma unroll
    for (int nt = 0; nt < 3; ++nt){
      float bv = proj_b[wave*48 + nt*16 + l15];
      pj[mt][nt] = {bv, bv, bv, bv};
    }

  #pragma unroll 1
  for (int h = 0; h < 6; ++h){
    const f32x4 z = {0.f, 0.f, 0.f, 0.f};
    // ---- QK^T: A,B frags straight from global ----
    bf16x8 qf = gfrag(Qg + wbase + (size_t)(wave*16 + l15)*192 + h*32 + kg*8);
    f32x4 at[4];
    #pragma unroll
    for (int nt = 0; nt < 4; ++nt){
      bf16x8 kf = gfrag(Kg + wbase + (size_t)(nt*16 + l15)*192 + h*32 + kg*8);
      at[nt] = MFMA16(qf, kf, z);
    }
    // ---- + rpb^T + mask (symmetric -> transposed load is direct) ----
    {
      const float* rb = rpbmT + h*4096;
      const float* mb = mask + (size_t)wm*4096;
      #pragma unroll
      for (int nt = 0; nt < 4; ++nt){
        int cidx = (nt*16 + l15)*64 + wave*16 + kg*4;
        float4 r4 = *(const float4*)(rb + cidx);
        float4 m4 = *(const float4*)(mb + cidx);
        at[nt][0] += r4.x + m4.x;
        at[nt][1] += r4.y + m4.y;
        at[nt][2] += r4.z + m4.z;
        at[nt][3] += r4.w + m4.w;
      }
    }
    // ---- softmax (16-lane group) ----
    #pragma unroll
    for (int r = 0; r < 4; ++r){
      float m0 = fmaxf(fmaxf(at[0][r], at[1][r]), fmaxf(at[2][r], at[3][r]));
      #pragma unroll
      for (int mk = 1; mk < 16; mk <<= 1) m0 = fmaxf(m0, __shfl_xor(m0, mk));
      float s = 0.f;
      #pragma unroll
      for (int nt = 0; nt < 4; ++nt){ at[nt][r] = __expf(at[nt][r] - m0); s += at[nt][r]; }
      #pragma unroll
      for (int mk = 1; mk < 16; mk <<= 1) s += __shfl_xor(s, mk);
      float inv = 1.0f / s;
      #pragma unroll
      for (int nt = 0; nt < 4; ++nt) at[nt][r] *= inv;
    }
    // ---- P -> LDS (wave-local rows; no barrier needed) ----
    #pragma unroll
    for (int nt = 0; nt < 4; ++nt)
      #pragma unroll
      for (int r = 0; r < 4; ++r)
        prb[(wave*16 + kg*4 + r)*72 + nt*16 + l15] = f2bf(at[nt][r]);
    // ---- PV: P from LDS (transposed), V^T from global ----
    {
      f32x4 ov[2] = {z, z};
      #pragma unroll
      for (int kt = 0; kt < 2; ++kt){
        bf16x8 pf = ldsfrag(prb + (wave*16 + l15)*72 + kt*32 + kg*8);
        #pragma unroll
        for (int d = 0; d < 2; ++d){
          bf16x8 vf = gfrag(VTg + wbase + (size_t)(h*32 + d*16 + l15)*64 + kt*32 + kg*8);
          ov[d] = MFMA16(pf, vf, ov[d]);
        }
      }
      #pragma unroll
      for (int d = 0; d < 2; ++d)
        #pragma unroll
        for (int r = 0; r < 4; ++r)
          obuf[(wave*16 + kg*4 + r)*200 + h*32 + d*16 + l15] = f2bf(ov[d][r]);
    }
  }
  __syncthreads();

  // ---- proj: wave owns out cols [wave*48,+48), K=192 ----
  #pragma unroll 2
  for (int kt = 0; kt < 6; ++kt){
    bf16x8 af[4];
    #pragma unroll
    for (int mt = 0; mt < 4; ++mt)
      af[mt] = ldsfrag(obuf + (mt*16 + l15)*200 + kt*32 + kg*8);
    #pragma unroll
    for (int nt = 0; nt < 3; ++nt){
      bf16x8 bfr = gfrag(proj_bf + (wave*48 + nt*16 + l15)*192 + kt*32 + kg*8);
      #pragma unroll
      for (int mt = 0; mt < 4; ++mt)
        pj[mt][nt] = MFMA16(af[mt], bfr, pj[mt][nt]);
    }
  }

  // ---- LN1 + residual, scatter to un-shifted coords ----
  float gv[3], bv2[3];
  #pragma unroll
  for (int nt = 0; nt < 3; ++nt){
    int c = wave*48 + nt*16 + l15;
    gv[nt] = n1g[c]; bv2[nt] = n1b[c];
  }
  #pragma unroll
  for (int mt = 0; mt < 4; ++mt)
    #pragma unroll
    for (int r = 0; r < 4; ++r){
      float s1 = pj[mt][0][r] + pj[mt][1][r] + pj[mt][2][r];
      float s2 = pj[mt][0][r]*pj[mt][0][r] + pj[mt][1][r]*pj[mt][1][r] + pj[mt][2][r]*pj[mt][2][r];
      #pragma unroll
      for (int mk = 1; mk < 16; mk <<= 1){ s1 += __shfl_xor(s1, mk); s2 += __shfl_xor(s2, mk); }
      if (l15 == 0){
        int t = mt*16 + kg*4 + r;
        lnred[t*8 + wave*2]     = s1;
        lnred[t*8 + wave*2 + 1] = s2;
      }
    }
  __syncthreads();
  #pragma unroll
  for (int mt = 0; mt < 4; ++mt)
    #pragma unroll 1
    for (int r = 0; r < 4; ++r){
      int t = mt*16 + kg*4 + r;
      float a1 = lnred[t*8+0] + lnred[t*8+2] + lnred[t*8+4] + lnred[t*8+6];
      float a2 = lnred[t*8+1] + lnred[t*8+3] + lnred[t*8+5] + lnred[t*8+7];
      float mu = a1 * (1.f/192.f);
      float rs = rsqrtf(a2 * (1.f/192.f) - mu*mu + LN_EPS);
      int i = t >> 3, j = t & 7;
      int h0 = ((wh<<3) + i + 4) & 255, w0 = ((ww<<3) + j + 4) & 255;
      size_t base = imgbase + (size_t)(h0*256 + w0)*192;
      #pragma unroll
      for (int nt = 0; nt < 3; ++nt){
        int c = wave*48 + nt*16 + l15;
        x1[base + c] = x[base + c] + (pj[mt][nt][r] - mu)*rs*gv[nt] + bv2[nt];
      }
    }
}

// =====================================================================
// K1 (fallback, round-4 proven): monolithic attention
// =====================================================================
__global__ __launch_bounds__(256, 3) void k_attn(
    const float* __restrict__ x, const float* __restrict__ mask,
    const float* __restrict__ rpbm, const u16* __restrict__ qkv_bf,
    const float* __restrict__ qkv_b, const u16* __restrict__ proj_bf,
    const float* __restrict__ proj_b, const float* __restrict__ n1g,
    const float* __restrict__ n1b, float* __restrict__ x1)
{
  __shared__ __align__(16) u16 xw[64*200];
  __shared__ __align__(16) u16 qkvh[64*72];
  __shared__ __align__(16) u16 vT[32*72];
  __shared__ __align__(16) u16 prb[64*72];
  __shared__ __align__(16) u16 outh[64*40];
  float* lnred = (float*)outh;

  const int tid  = threadIdx.x;
  const int wave = tid >> 6, lane = tid & 63;
  const int kg   = lane >> 4, l15 = lane & 15;
  const int wi = blockIdx.x;
  const int b  = wi >> 10, wm = wi & 1023;
  const int wh = wm >> 5,  ww = wm & 31;
  const size_t imgbase = (size_t)b * (256*256*192);

  for (int s = tid; s < 64*96; s += 256){
    int t = s / 96, c2 = s - t*96;
    int i = t >> 3, j = t & 7;
    int h0 = ((wh<<3) + i + 4) & 255;
    int w0 = ((ww<<3) + j + 4) & 255;
    float2 v = LDF2(x + imgbase + (size_t)(h0*256 + w0)*192 + c2*2);
    ST_U32(xw + t*200 + c2*2, pack2(v.x, v.y));
  }

  f32x4 pj[4][3];
  #pragma unroll
  for (int mt = 0; mt < 4; ++mt)
    #pragma unroll
    for (int nt = 0; nt < 3; ++nt){
      float bv = proj_b[wave*48 + nt*16 + l15];
      pj[mt][nt] = {bv, bv, bv, bv};
    }
  __syncthreads();

  #pragma unroll 1
  for (int h = 0; h < 6; ++h){
    f32x4 qa[6];
    #pragma unroll
    for (int nt = 0; nt < 6; ++nt){
      float bv = qkv_b[(nt>>1)*192 + h*32 + (nt&1)*16 + l15];
      qa[nt] = {bv, bv, bv, bv};
    }
    #pragma unroll 2
    for (int kt = 0; kt < 6; ++kt){
      bf16x8 af = ldsfrag(xw + (wave*16 + l15)*200 + kt*32 + kg*8);
      #pragma unroll
      for (int nt = 0; nt < 6; ++nt){
        bf16x8 bfr = gfrag(qkv_bf + ((nt>>1)*192 + h*32 + (nt&1)*16 + l15)*192 + kt*32 + kg*8);
        qa[nt] = MFMA16(af, bfr, qa[nt]);
      }
    }
    #pragma unroll
    for (int nt = 0; nt < 2; ++nt)
      #pragma unroll
      for (int r = 0; r < 4; ++r)
        qkvh[(wave*16 + kg*4 + r)*72 + nt*16 + l15] = f2bf(qa[nt][r]*SCALE_Q);
    #pragma unroll
    for (int nt = 2; nt < 4; ++nt)
      #pragma unroll
      for (int r = 0; r < 4; ++r)
        qkvh[(wave*16 + kg*4 + r)*72 + 32 + (nt-2)*16 + l15] = f2bf(qa[nt][r]);
    #pragma unroll
    for (int nt = 4; nt < 6; ++nt)
      #pragma unroll
      for (int r = 0; r < 4; ++r)
        vT[((nt-4)*16 + l15)*72 + wave*16 + kg*4 + r] = f2bf(qa[nt][r]);
    __syncthreads();

    f32x4 at[4];
    {
      const f32x4 z = {0.f, 0.f, 0.f, 0.f};
      bf16x8 qf = ldsfrag(qkvh + (wave*16 + l15)*72 + kg*8);
      #pragma unroll
      for (int nt = 0; nt < 4; ++nt){
        bf16x8 kf = ldsfrag(qkvh + (nt*16 + l15)*72 + 32 + kg*8);
        at[nt] = MFMA16(qf, kf, z);
      }
    }
    {
      const float* rb = rpbm + h*4096;
      const float* mb = mask + (size_t)wm*4096;
      #pragma unroll
      for (int nt = 0; nt < 4; ++nt)
        #pragma unroll
        for (int r = 0; r < 4; ++r){
          int idx = (wave*16 + kg*4 + r)*64 + nt*16 + l15;
          at[nt][r] += rb[idx] + mb[idx];
        }
    }
    #pragma unroll
    for (int r = 0; r < 4; ++r){
      float m0 = fmaxf(fmaxf(at[0][r], at[1][r]), fmaxf(at[2][r], at[3][r]));
      #pragma unroll
      for (int mk = 1; mk < 16; mk <<= 1) m0 = fmaxf(m0, __shfl_xor(m0, mk));
      float s = 0.f;
      #pragma unroll
      for (int nt = 0; nt < 4; ++nt){ at[nt][r] = __expf(at[nt][r] - m0); s += at[nt][r]; }
      #pragma unroll
      for (int mk = 1; mk < 16; mk <<= 1) s += __shfl_xor(s, mk);
      float inv = 1.0f / s;
      #pragma unroll
      for (int nt = 0; nt < 4; ++nt) at[nt][r] *= inv;
    }
    #pragma unroll
    for (int nt = 0; nt < 4; ++nt)
      #pragma unroll
      for (int r = 0; r < 4; ++r)
        prb[(wave*16 + kg*4 + r)*72 + nt*16 + l15] = f2bf(at[nt][r]);

    {
      f32x4 ov[2] = {{0,0,0,0},{0,0,0,0}};
      #pragma unroll
      for (int kt = 0; kt < 2; ++kt){
        bf16x8 pf = ldsfrag(prb + (wave*16 + l15)*72 + kt*32 + kg*8);
        #pragma unroll
        for (int nt = 0; nt < 2; ++nt){
          bf16x8 vf = ldsfrag(vT + (nt*16 + l15)*72 + kt*32 + kg*8);
          ov[nt] = MFMA16(pf, vf, ov[nt]);
        }
      }
      #pragma unroll
      for (int nt = 0; nt < 2; ++nt)
        #pragma unroll
        for (int r = 0; r < 4; ++r)
          outh[(wave*16 + kg*4 + r)*40 + nt*16 + l15] = f2bf(ov[nt][r]);
    }
    __syncthreads();

    {
      bf16x8 pw[3];
      #pragma unroll
      for (int nt = 0; nt < 3; ++nt)
        pw[nt] = gfrag(proj_bf + (wave*48 + nt*16 + l15)*192 + h*32 + kg*8);
      #pragma unroll
      for (int mt = 0; mt < 4; ++mt){
        bf16x8 af = ldsfrag(outh + (mt*16 + l15)*40 + kg*8);
        #pragma unroll
        for (int nt = 0; nt < 3; ++nt)
          pj[mt][nt] = MFMA16(af, pw[nt], pj[mt][nt]);
      }
    }
    __syncthreads();
  }

  float gv[3], bv2[3];
  #pragma unroll
  for (int nt = 0; nt < 3; ++nt){
    int c = wave*48 + nt*16 + l15;
    gv[nt] = n1g[c]; bv2[nt] = n1b[c];
  }
  #pragma unroll
  for (int mt = 0; mt < 4; ++mt)
    #pragma unroll
    for (int r = 0; r < 4; ++r){
      float s1 = pj[mt][0][r] + pj[mt][1][r] + pj[mt][2][r];
      float s2 = pj[mt][0][r]*pj[mt][0][r] + pj[mt][1][r]*pj[mt][1][r] + pj[mt][2][r]*pj[mt][2][r];
      #pragma unroll
      for (int mk = 1; mk < 16; mk <<= 1){ s1 += __shfl_xor(s1, mk); s2 += __shfl_xor(s2, mk); }
      if (l15 == 0){
        int t = mt*16 + kg*4 + r;
        lnred[t*8 + wave*2]     = s1;
        lnred[t*8 + wave*2 + 1] = s2;
      }
    }
  __syncthreads();
  #pragma unroll
  for (int mt = 0; mt < 4; ++mt)
    #pragma unroll 1
    for (int r = 0; r < 4; ++r){
      int t = mt*16 + kg*4 + r;
      float a1 = lnred[t*8+0] + lnred[t*8+2] + lnred[t*8+4] + lnred[t*8+6];
      float a2 = lnred[t*8+1] + lnred[t*8+3] + lnred[t*8+5] + lnred[t*8+7];
      float mu = a1 * (1.f/192.f);
      float rs = rsqrtf(a2 * (1.f/192.f) - mu*mu + LN_EPS);
      int i = t >> 3, j = t & 7;
      int h0 = ((wh<<3) + i + 4) & 255, w0 = ((ww<<3) + j + 4) & 255;
      size_t base = imgbase + (size_t)(h0*256 + w0)*192;
      #pragma unroll
      for (int nt = 0; nt < 3; ++nt){
        int c = wave*48 + nt*16 + l15;
        x1[base + c] = x[base + c] + (pj[mt][nt][r] - mu)*rs*gv[nt] + bv2[nt];
      }
    }
}

// =====================================================================
// K2: MLP (fc1 + GELU + fc2) + LN2 + residual, IN-PLACE on xio (f32)
// =====================================================================
__global__ __launch_bounds__(256, 3) void k_mlp(
    float* xio, const u16* __restrict__ fc1_bf,
    const float* __restrict__ fc1_b, const u16* __restrict__ fc2_bf,
    const float* __restrict__ fc2_b, const float* __restrict__ n2g,
    const float* __restrict__ n2b)
{
  __shared__ __align__(16) u16 xt[64*200];
  __shared__ __align__(16) u16 hl[64*200];
  __shared__ float lnred[64*8];

  const int tid  = threadIdx.x;
  const int wave = tid >> 6, lane = tid & 63;
  const int kg   = lane >> 4, l15 = lane & 15;
  const size_t t0 = (size_t)blockIdx.x * 64;

  for (int s = tid; s < 64*96; s += 256){
    int t = s / 96, c2 = s - t*96;
    float2 v = LDF2(xio + (t0 + t)*192 + c2*2);
    ST_U32(xt + t*200 + c2*2, pack2(v.x, v.y));
  }
  f32x4 m2[4][3];
  #pragma unroll
  for (int mt = 0; mt < 4; ++mt)
    #pragma unroll
    for (int nt = 0; nt < 3; ++nt){
      float bv = fc2_b[wave*48 + nt*16 + l15];
      m2[mt][nt] = {bv, bv, bv, bv};
    }
  __syncthreads();

  #pragma unroll 1
  for (int c = 0; c < 4; ++c){
    f32x4 a1[4][3];
    #pragma unroll
    for (int mt = 0; mt < 4; ++mt)
      #pragma unroll
      for (int nt = 0; nt < 3; ++nt){
        float bv = fc1_b[c*192 + wave*48 + nt*16 + l15];
        a1[mt][nt] = {bv, bv, bv, bv};
      }
    #pragma unroll 2
    for (int kt = 0; kt < 6; ++kt){
      bf16x8 af[4];
      #pragma unroll
      for (int mt = 0; mt < 4; ++mt)
        af[mt] = ldsfrag(xt + (mt*16 + l15)*200 + kt*32 + kg*8);
      #pragma unroll
      for (int nt = 0; nt < 3; ++nt){
        bf16x8 bfr = gfrag(fc1_bf + (size_t)(c*192 + wave*48 + nt*16 + l15)*192 + kt*32 + kg*8);
        #pragma unroll
        for (int mt = 0; mt < 4; ++mt)
          a1[mt][nt] = MFMA16(af[mt], bfr, a1[mt][nt]);
      }
    }
    #pragma unroll
    for (int mt = 0; mt < 4; ++mt)
      #pragma unroll
      for (int nt = 0; nt < 3; ++nt)
        #pragma unroll
        for (int r = 0; r < 4; ++r)
          hl[(mt*16 + kg*4 + r)*200 + wave*48 + nt*16 + l15] = f2bf(gelu_f(a1[mt][nt][r]));
    __syncthreads();

    #pragma unroll 2
    for (int kt = 0; kt < 6; ++kt){
      bf16x8 af[4];
      #pragma unroll
      for (int mt = 0; mt < 4; ++mt)
        af[mt] = ldsfrag(hl + (mt*16 + l15)*200 + kt*32 + kg*8);
      #pragma unroll
      for (int nt = 0; nt < 3; ++nt){
        bf16x8 bfr = gfrag(fc2_bf + (size_t)(wave*48 + nt*16 + l15)*768 + c*192 + kt*32 + kg*8);
        #pragma unroll
        for (int mt = 0; mt < 4; ++mt)
          m2[mt][nt] = MFMA16(af[mt], bfr, m2[mt][nt]);
      }
    }
    __syncthreads();
  }

  float gv[3], bv2[3];
  #pragma unroll
  for (int nt = 0; nt < 3; ++nt){
    int cc = wave*48 + nt*16 + l15;
    gv[nt] = n2g[cc]; bv2[nt] = n2b[cc];
  }
  #pragma unroll
  for (int mt = 0; mt < 4; ++mt)
    #pragma unroll
    for (int r = 0; r < 4; ++r){
      float s1 = m2[mt][0][r] + m2[mt][1][r] + m2[mt][2][r];
      float s2 = m2[mt][0][r]*m2[mt][0][r] + m2[mt][1][r]*m2[mt][1][r] + m2[mt][2][r]*m2[mt][2][r];
      #pragma unroll
      for (int mk = 1; mk < 16; mk <<= 1){ s1 += __shfl_xor(s1, mk); s2 += __shfl_xor(s2, mk); }
      if (l15 == 0){
        int t = mt*16 + kg*4 + r;
        lnred[t*8 + wave*2]     = s1;
        lnred[t*8 + wave*2 + 1] = s2;
      }
    }
  __syncthreads();
  #pragma unroll
  for (int mt = 0; mt < 4; ++mt)
    #pragma unroll 1
    for (int r = 0; r < 4; ++r){
      int t = mt*16 + kg*4 + r;
      float a1s = lnred[t*8+0] + lnred[t*8+2] + lnred[t*8+4] + lnred[t*8+6];
      float a2s = lnred[t*8+1] + lnred[t*8+3] + lnred[t*8+5] + lnred[t*8+7];
      float mu = a1s * (1.f/192.f);
      float rs = rsqrtf(a2s * (1.f/192.f) - mu*mu + LN_EPS);
      size_t base = (t0 + t)*192;
      #pragma unroll
      for (int nt = 0; nt < 3; ++nt){
        int cc = wave*48 + nt*16 + l15;
        xio[base + cc] = xio[base + cc] + (m2[mt][nt][r] - mu)*rs*gv[nt] + bv2[nt];
      }
    }
}

extern "C" void kernel_launch(void* const* d_in, const int* in_sizes, int n_in,
                              void* d_out, int out_size, void* d_ws, size_t ws_size,
                              hipStream_t stream)
{
  const float* x      = (const float*)d_in[0];
  const float* mask   = (const float*)d_in[1];
  const int*   relidx = (const int*)d_in[2];
  const float* qkv_w  = (const float*)d_in[3];
  const float* qkv_b  = (const float*)d_in[4];
  const float* proj_w = (const float*)d_in[5];
  const float* proj_b = (const float*)d_in[6];
  const float* rpb    = (const float*)d_in[7];
  const float* n1g    = (const float*)d_in[8];
  const float* n1b    = (const float*)d_in[9];
  const float* n2g    = (const float*)d_in[10];
  const float* n2b    = (const float*)d_in[11];
  const float* fc1_w  = (const float*)d_in[12];
  const float* fc1_b  = (const float*)d_in[13];
  const float* fc2_w  = (const float*)d_in[14];
  const float* fc2_b  = (const float*)d_in[15];
  float* xio = (float*)d_out;

  u16* qkv_bf  = (u16*)d_ws;
  u16* proj_bf = qkv_bf + NQKV;
  u16* fc1_bf  = proj_bf + NPRJ;
  u16* fc2_bf  = fc1_bf + NFC;
  float* rpbm  = (float*)(fc2_bf + NFC);
  float* rpbmT = rpbm + 6*4096;
  u16* Qg = (u16*)((char*)d_ws + WS_SPLIT_HDR);
  u16* Kg = Qg + QKV_SLAB;
  u16* VTg = Kg + QKV_SLAB;

  const int split = (ws_size >= WS_SPLIT_NEED) ? 1 : 0;

  k_prep<<<dim3(512), dim3(256), 0, stream>>>(qkv_w, proj_w, fc1_w, fc2_w,
      rpb, relidx, qkv_bf, proj_bf, fc1_bf, fc2_bf, rpbm, rpbmT, split);
  if (split){
    k_qkv<<<dim3(4096), dim3(256), 0, stream>>>(x, qkv_bf, qkv_b, Qg, Kg, VTg);
    k_attn2<<<dim3(4096), dim3(256), 0, stream>>>(x, mask, rpbmT, Qg, Kg, VTg,
        proj_bf, proj_b, n1g, n1b, xio);
  } else {
    k_attn<<<dim3(4096), dim3(256), 0, stream>>>(x, mask, rpbm, qkv_bf, qkv_b,
        proj_bf, proj_b, n1g, n1b, xio);
  }
  k_mlp<<<dim3(4096), dim3(256), 0, stream>>>(xio, fc1_bf, fc1_b, fc2_bf, fc2_b,
      n2g, n2b);
}

// Round 7
// 939.231 us; speedup vs baseline: 6.1731x; 1.0005x over previous
//
#include <hip/hip_runtime.h>
#include <hip/hip_bf16.h>
#include <math.h>

typedef unsigned short u16;
typedef unsigned int   u32;
typedef __attribute__((ext_vector_type(8))) short bf16x8;   // 8 bf16 = 4 VGPR
typedef __attribute__((ext_vector_type(4))) float f32x4;

__device__ __forceinline__ u16 f2bf(float f){
  u32 u = __float_as_uint(f);
  u += 0x7fffu + ((u>>16)&1u);          // RNE; inputs never NaN
  return (u16)(u>>16);
}
__device__ __forceinline__ u32 pack2(float a, float b){
  return (u32)f2bf(a) | ((u32)f2bf(b)<<16);
}
__device__ __forceinline__ float2 LDF2(const float* p){ return *(const float2*)p; }
__device__ __forceinline__ float gelu_f(float v){
  float t = __expf(1.5957691216057308f * fmaf(0.044715f*v, v*v, v));
  return v - v/(t + 1.0f);
}

#define ST_U32(p,v) (*(u32*)(p) = (v))
#define MFMA16(a,b,c) __builtin_amdgcn_mfma_f32_16x16x32_bf16((a),(b),(c),0,0,0)

__device__ __forceinline__ bf16x8 ldsfrag(const u16* p){ return *(const bf16x8*)p; }
__device__ __forceinline__ bf16x8 gfrag(const u16* p){ return *(const bf16x8*)p; }

constexpr float SCALE_Q = 0.17677669529663687f;  // 32^-0.5
constexpr float LN_EPS  = 1e-5f;

// ws element counts (u16)
#define NQKV 110592
#define NPRJ 36864
#define NFC  147456
#define QKV_SLAB 50331648ull        // 4096*64*192 u16 per Q/K/VT slab
#define WS_WEIGHTS_B 884736ull
#define WS_RPBM_B    98304ull
#define WS_SPLIT_HDR (WS_WEIGHTS_B + 2*WS_RPBM_B)   // 1081344
#define WS_SPLIT_NEED (WS_SPLIT_HDR + 3ull*QKV_SLAB*2ull)

// =====================================================================
// K0: weight f32->bf16 conversion + rpb gather (row-major, + transposed if mode)
// =====================================================================
__global__ void k_prep(const float* __restrict__ qkv_w, const float* __restrict__ proj_w,
                       const float* __restrict__ fc1_w, const float* __restrict__ fc2_w,
                       const float* __restrict__ rpb, const int* __restrict__ relidx,
                       u16* __restrict__ qkv_bf, u16* __restrict__ proj_bf,
                       u16* __restrict__ fc1_bf, u16* __restrict__ fc2_bf,
                       float* __restrict__ rpbm, float* __restrict__ rpbmT, int mode)
{
  int stride = gridDim.x * blockDim.x;
  int t = blockIdx.x * blockDim.x + threadIdx.x;
  for (int i = t; i < NQKV; i += stride) qkv_bf[i] = f2bf(qkv_w[i]);
  for (int i = t; i < NPRJ; i += stride) proj_bf[i] = f2bf(proj_w[i]);
  for (int i = t; i < NFC;  i += stride) fc1_bf[i]  = f2bf(fc1_w[i]);
  for (int i = t; i < NFC;  i += stride) fc2_bf[i]  = f2bf(fc2_w[i]);
  for (int i = t; i < 6*4096; i += stride){
    int h = i >> 12, ij = i & 4095;
    rpbm[i] = rpb[relidx[ij]*6 + h];
  }
  if (mode){
    for (int i = t; i < 6*4096; i += stride){
      int h = i >> 12, ij = i & 4095;           // ij = col*64 + row (transposed)
      int col = ij >> 6, row = ij & 63;
      rpbmT[i] = rpb[relidx[row*64 + col]*6 + h];
    }
  }
}

// =====================================================================
// K1a (split path): per-window qkv GEMM -> Qg (scaled), Kg, VTg (transposed)
// block = window, 4 waves; 1 barrier
// =====================================================================
__global__ __launch_bounds__(256, 4) void k_qkv(
    const float* __restrict__ x, const u16* __restrict__ qkv_bf,
    const float* __restrict__ qkv_b,
    u16* __restrict__ Qg, u16* __restrict__ Kg, u16* __restrict__ VTg)
{
  __shared__ __align__(16) u16 xw[64*200];
  const int tid = threadIdx.x, wave = tid >> 6, lane = tid & 63;
  const int kg = lane >> 4, l15 = lane & 15;
  const int wi = blockIdx.x, b = wi >> 10, wm = wi & 1023;
  const int wh = wm >> 5, ww = wm & 31;
  const size_t imgbase = (size_t)b * (256*256*192);

  for (int s = tid; s < 64*96; s += 256){
    int t = s / 96, c2 = s - t*96;
    int i = t >> 3, j = t & 7;
    int h0 = ((wh<<3) + i + 4) & 255;
    int w0 = ((ww<<3) + j + 4) & 255;
    float2 v = LDF2(x + imgbase + (size_t)(h0*256 + w0)*192 + c2*2);
    ST_U32(xw + t*200 + c2*2, pack2(v.x, v.y));
  }
  __syncthreads();

  const size_t wbase = (size_t)wi * 12288;
  #pragma unroll 1
  for (int batch = 0; batch < 3; ++batch){
    const int col0 = wave*144 + batch*48;
    f32x4 a[4][3];
    #pragma unroll
    for (int j = 0; j < 3; ++j){
      float bv = qkv_b[col0 + j*16 + l15];
      #pragma unroll
      for (int mt = 0; mt < 4; ++mt) a[mt][j] = {bv, bv, bv, bv};
    }
    #pragma unroll 2
    for (int kt = 0; kt < 6; ++kt){
      bf16x8 af[4];
      #pragma unroll
      for (int mt = 0; mt < 4; ++mt)
        af[mt] = ldsfrag(xw + (mt*16 + l15)*200 + kt*32 + kg*8);
      #pragma unroll
      for (int j = 0; j < 3; ++j){
        bf16x8 bfr = gfrag(qkv_bf + (col0 + j*16 + l15)*192 + kt*32 + kg*8);
        #pragma unroll
        for (int mt = 0; mt < 4; ++mt)
          a[mt][j] = MFMA16(af[mt], bfr, a[mt][j]);
      }
    }
    #pragma unroll
    for (int j = 0; j < 3; ++j){
      int colg = col0 + j*16 + l15;          // uniform section per (wave,batch,j)
      if (colg < 192){
        #pragma unroll
        for (int mt = 0; mt < 4; ++mt)
          #pragma unroll
          for (int r = 0; r < 4; ++r)
            Qg[wbase + (size_t)(mt*16 + kg*4 + r)*192 + colg] = f2bf(a[mt][j][r]*SCALE_Q);
      } else if (colg < 384){
        #pragma unroll
        for (int mt = 0; mt < 4; ++mt)
          #pragma unroll
          for (int r = 0; r < 4; ++r)
            Kg[wbase + (size_t)(mt*16 + kg*4 + r)*192 + (colg - 192)] = f2bf(a[mt][j][r]);
      } else {
        #pragma unroll
        for (int mt = 0; mt < 4; ++mt){
          ushort4 pk = { f2bf(a[mt][j][0]), f2bf(a[mt][j][1]),
                         f2bf(a[mt][j][2]), f2bf(a[mt][j][3]) };
          *(ushort4*)(VTg + wbase + (size_t)(colg - 384)*64 + mt*16 + kg*4) = pk;
        }
      }
    }
  }
}

// =====================================================================
// K1b (split path): attention core + proj + LN1 + residual -> x1
// block = window, 4 waves (wave = 16 query rows); 3 barriers total
// =====================================================================
__global__ __launch_bounds__(256, 4) void k_attn2(
    const float* __restrict__ x, const float* __restrict__ mask,
    const float* __restrict__ rpbmT,
    const u16* __restrict__ Qg, const u16* __restrict__ Kg,
    const u16* __restrict__ VTg,
    const u16* __restrict__ proj_bf, const float* __restrict__ proj_b,
    const float* __restrict__ n1g, const float* __restrict__ n1b,
    float* __restrict__ x1)
{
  __shared__ __align__(16) u16 prb[64*72];
  __shared__ __align__(16) u16 obuf[64*200];
  __shared__ float lnred[64*8];

  const int tid = threadIdx.x, wave = tid >> 6, lane = tid & 63;
  const int kg = lane >> 4, l15 = lane & 15;
  const int wi = blockIdx.x, b = wi >> 10, wm = wi & 1023;
  const int wh = wm >> 5, ww = wm & 31;
  const size_t imgbase = (size_t)b * (256*256*192);
  const size_t wbase = (size_t)wi * 12288;

  f32x4 pj[4][3];
  #pragma unroll
  for (int mt = 0; mt < 4; ++mt)
    #pragma unroll
    for (int nt = 0; nt < 3; ++nt){
      float bv = proj_b[wave*48 + nt*16 + l15];
      pj[mt][nt] = {bv, bv, bv, bv};
    }

  #pragma unroll 1
  for (int h = 0; h < 6; ++h){
    const f32x4 z = {0.f, 0.f, 0.f, 0.f};
    // ---- QK^T: A,B frags straight from global ----
    bf16x8 qf = gfrag(Qg + wbase + (size_t)(wave*16 + l15)*192 + h*32 + kg*8);
    f32x4 at[4];
    #pragma unroll
    for (int nt = 0; nt < 4; ++nt){
      bf16x8 kf = gfrag(Kg + wbase + (size_t)(nt*16 + l15)*192 + h*32 + kg*8);
      at[nt] = MFMA16(qf, kf, z);
    }
    // ---- + rpb^T + mask (symmetric -> transposed load is direct) ----
    {
      const float* rb = rpbmT + h*4096;
      const float* mb = mask + (size_t)wm*4096;
      #pragma unroll
      for (int nt = 0; nt < 4; ++nt){
        int cidx = (nt*16 + l15)*64 + wave*16 + kg*4;
        float4 r4 = *(const float4*)(rb + cidx);
        float4 m4 = *(const float4*)(mb + cidx);
        at[nt][0] += r4.x + m4.x;
        at[nt][1] += r4.y + m4.y;
        at[nt][2] += r4.z + m4.z;
        at[nt][3] += r4.w + m4.w;
      }
    }
    // ---- softmax (16-lane group) ----
    #pragma unroll
    for (int r = 0; r < 4; ++r){
      float m0 = fmaxf(fmaxf(at[0][r], at[1][r]), fmaxf(at[2][r], at[3][r]));
      #pragma unroll
      for (int mk = 1; mk < 16; mk <<= 1) m0 = fmaxf(m0, __shfl_xor(m0, mk));
      float s = 0.f;
      #pragma unroll
      for (int nt = 0; nt < 4; ++nt){ at[nt][r] = __expf(at[nt][r] - m0); s += at[nt][r]; }
      #pragma unroll
      for (int mk = 1; mk < 16; mk <<= 1) s += __shfl_xor(s, mk);
      float inv = 1.0f / s;
      #pragma unroll
      for (int nt = 0; nt < 4; ++nt) at[nt][r] *= inv;
    }
    // ---- P -> LDS (wave-local rows; no barrier needed) ----
    #pragma unroll
    for (int nt = 0; nt < 4; ++nt)
      #pragma unroll
      for (int r = 0; r < 4; ++r)
        prb[(wave*16 + kg*4 + r)*72 + nt*16 + l15] = f2bf(at[nt][r]);
    // ---- PV: P from LDS (transposed), V^T from global ----
    {
      f32x4 ov[2] = {z, z};
      #pragma unroll
      for (int kt = 0; kt < 2; ++kt){
        bf16x8 pf = ldsfrag(prb + (wave*16 + l15)*72 + kt*32 + kg*8);
        #pragma unroll
        for (int d = 0; d < 2; ++d){
          bf16x8 vf = gfrag(VTg + wbase + (size_t)(h*32 + d*16 + l15)*64 + kt*32 + kg*8);
          ov[d] = MFMA16(pf, vf, ov[d]);
        }
      }
      #pragma unroll
      for (int d = 0; d < 2; ++d)
        #pragma unroll
        for (int r = 0; r < 4; ++r)
          obuf[(wave*16 + kg*4 + r)*200 + h*32 + d*16 + l15] = f2bf(ov[d][r]);
    }
  }
  __syncthreads();

  // ---- proj: wave owns out cols [wave*48,+48), K=192 ----
  #pragma unroll 2
  for (int kt = 0; kt < 6; ++kt){
    bf16x8 af[4];
    #pragma unroll
    for (int mt = 0; mt < 4; ++mt)
      af[mt] = ldsfrag(obuf + (mt*16 + l15)*200 + kt*32 + kg*8);
    #pragma unroll
    for (int nt = 0; nt < 3; ++nt){
      bf16x8 bfr = gfrag(proj_bf + (wave*48 + nt*16 + l15)*192 + kt*32 + kg*8);
      #pragma unroll
      for (int mt = 0; mt < 4; ++mt)
        pj[mt][nt] = MFMA16(af[mt], bfr, pj[mt][nt]);
    }
  }

  // ---- LN1 + residual, scatter to un-shifted coords ----
  float gv[3], bv2[3];
  #pragma unroll
  for (int nt = 0; nt < 3; ++nt){
    int c = wave*48 + nt*16 + l15;
    gv[nt] = n1g[c]; bv2[nt] = n1b[c];
  }
  #pragma unroll
  for (int mt = 0; mt < 4; ++mt)
    #pragma unroll
    for (int r = 0; r < 4; ++r){
      float s1 = pj[mt][0][r] + pj[mt][1][r] + pj[mt][2][r];
      float s2 = pj[mt][0][r]*pj[mt][0][r] + pj[mt][1][r]*pj[mt][1][r] + pj[mt][2][r]*pj[mt][2][r];
      #pragma unroll
      for (int mk = 1; mk < 16; mk <<= 1){ s1 += __shfl_xor(s1, mk); s2 += __shfl_xor(s2, mk); }
      if (l15 == 0){
        int t = mt*16 + kg*4 + r;
        lnred[t*8 + wave*2]     = s1;
        lnred[t*8 + wave*2 + 1] = s2;
      }
    }
  __syncthreads();
  #pragma unroll
  for (int mt = 0; mt < 4; ++mt)
    #pragma unroll 1
    for (int r = 0; r < 4; ++r){
      int t = mt*16 + kg*4 + r;
      float a1 = lnred[t*8+0] + lnred[t*8+2] + lnred[t*8+4] + lnred[t*8+6];
      float a2 = lnred[t*8+1] + lnred[t*8+3] + lnred[t*8+5] + lnred[t*8+7];
      float mu = a1 * (1.f/192.f);
      float rs = rsqrtf(a2 * (1.f/192.f) - mu*mu + LN_EPS);
      int i = t >> 3, j = t & 7;
      int h0 = ((wh<<3) + i + 4) & 255, w0 = ((ww<<3) + j + 4) & 255;
      size_t base = imgbase + (size_t)(h0*256 + w0)*192;
      #pragma unroll
      for (int nt = 0; nt < 3; ++nt){
        int c = wave*48 + nt*16 + l15;
        x1[base + c] = x[base + c] + (pj[mt][nt][r] - mu)*rs*gv[nt] + bv2[nt];
      }
    }
}

// =====================================================================
// K1 (fallback, round-4 proven): monolithic attention
// =====================================================================
__global__ __launch_bounds__(256, 3) void k_attn(
    const float* __restrict__ x, const float* __restrict__ mask,
    const float* __restrict__ rpbm, const u16* __restrict__ qkv_bf,
    const float* __restrict__ qkv_b, const u16* __restrict__ proj_bf,
    const float* __restrict__ proj_b, const float* __restrict__ n1g,
    const float* __restrict__ n1b, float* __restrict__ x1)
{
  __shared__ __align__(16) u16 xw[64*200];
  __shared__ __align__(16) u16 qkvh[64*72];
  __shared__ __align__(16) u16 vT[32*72];
  __shared__ __align__(16) u16 prb[64*72];
  __shared__ __align__(16) u16 outh[64*40];
  float* lnred = (float*)outh;

  const int tid  = threadIdx.x;
  const int wave = tid >> 6, lane = tid & 63;
  const int kg   = lane >> 4, l15 = lane & 15;
  const int wi = blockIdx.x;
  const int b  = wi >> 10, wm = wi & 1023;
  const int wh = wm >> 5,  ww = wm & 31;
  const size_t imgbase = (size_t)b * (256*256*192);

  for (int s = tid; s < 64*96; s += 256){
    int t = s / 96, c2 = s - t*96;
    int i = t >> 3, j = t & 7;
    int h0 = ((wh<<3) + i + 4) & 255;
    int w0 = ((ww<<3) + j + 4) & 255;
    float2 v = LDF2(x + imgbase + (size_t)(h0*256 + w0)*192 + c2*2);
    ST_U32(xw + t*200 + c2*2, pack2(v.x, v.y));
  }

  f32x4 pj[4][3];
  #pragma unroll
  for (int mt = 0; mt < 4; ++mt)
    #pragma unroll
    for (int nt = 0; nt < 3; ++nt){
      float bv = proj_b[wave*48 + nt*16 + l15];
      pj[mt][nt] = {bv, bv, bv, bv};
    }
  __syncthreads();

  #pragma unroll 1
  for (int h = 0; h < 6; ++h){
    f32x4 qa[6];
    #pragma unroll
    for (int nt = 0; nt < 6; ++nt){
      float bv = qkv_b[(nt>>1)*192 + h*32 + (nt&1)*16 + l15];
      qa[nt] = {bv, bv, bv, bv};
    }
    #pragma unroll 2
    for (int kt = 0; kt < 6; ++kt){
      bf16x8 af = ldsfrag(xw + (wave*16 + l15)*200 + kt*32 + kg*8);
      #pragma unroll
      for (int nt = 0; nt < 6; ++nt){
        bf16x8 bfr = gfrag(qkv_bf + ((nt>>1)*192 + h*32 + (nt&1)*16 + l15)*192 + kt*32 + kg*8);
        qa[nt] = MFMA16(af, bfr, qa[nt]);
      }
    }
    #pragma unroll
    for (int nt = 0; nt < 2; ++nt)
      #pragma unroll
      for (int r = 0; r < 4; ++r)
        qkvh[(wave*16 + kg*4 + r)*72 + nt*16 + l15] = f2bf(qa[nt][r]*SCALE_Q);
    #pragma unroll
    for (int nt = 2; nt < 4; ++nt)
      #pragma unroll
      for (int r = 0; r < 4; ++r)
        qkvh[(wave*16 + kg*4 + r)*72 + 32 + (nt-2)*16 + l15] = f2bf(qa[nt][r]);
    #pragma unroll
    for (int nt = 4; nt < 6; ++nt)
      #pragma unroll
      for (int r = 0; r < 4; ++r)
        vT[((nt-4)*16 + l15)*72 + wave*16 + kg*4 + r] = f2bf(qa[nt][r]);
    __syncthreads();

    f32x4 at[4];
    {
      const f32x4 z = {0.f, 0.f, 0.f, 0.f};
      bf16x8 qf = ldsfrag(qkvh + (wave*16 + l15)*72 + kg*8);
      #pragma unroll
      for (int nt = 0; nt < 4; ++nt){
        bf16x8 kf = ldsfrag(qkvh + (nt*16 + l15)*72 + 32 + kg*8);
        at[nt] = MFMA16(qf, kf, z);
      }
    }
    {
      const float* rb = rpbm + h*4096;
      const float* mb = mask + (size_t)wm*4096;
      #pragma unroll
      for (int nt = 0; nt < 4; ++nt)
        #pragma unroll
        for (int r = 0; r < 4; ++r){
          int idx = (wave*16 + kg*4 + r)*64 + nt*16 + l15;
          at[nt][r] += rb[idx] + mb[idx];
        }
    }
    #pragma unroll
    for (int r = 0; r < 4; ++r){
      float m0 = fmaxf(fmaxf(at[0][r], at[1][r]), fmaxf(at[2][r], at[3][r]));
      #pragma unroll
      for (int mk = 1; mk < 16; mk <<= 1) m0 = fmaxf(m0, __shfl_xor(m0, mk));
      float s = 0.f;
      #pragma unroll
      for (int nt = 0; nt < 4; ++nt){ at[nt][r] = __expf(at[nt][r] - m0); s += at[nt][r]; }
      #pragma unroll
      for (int mk = 1; mk < 16; mk <<= 1) s += __shfl_xor(s, mk);
      float inv = 1.0f / s;
      #pragma unroll
      for (int nt = 0; nt < 4; ++nt) at[nt][r] *= inv;
    }
    #pragma unroll
    for (int nt = 0; nt < 4; ++nt)
      #pragma unroll
      for (int r = 0; r < 4; ++r)
        prb[(wave*16 + kg*4 + r)*72 + nt*16 + l15] = f2bf(at[nt][r]);

    {
      f32x4 ov[2] = {{0,0,0,0},{0,0,0,0}};
      #pragma unroll
      for (int kt = 0; kt < 2; ++kt){
        bf16x8 pf = ldsfrag(prb + (wave*16 + l15)*72 + kt*32 + kg*8);
        #pragma unroll
        for (int nt = 0; nt < 2; ++nt){
          bf16x8 vf = ldsfrag(vT + (nt*16 + l15)*72 + kt*32 + kg*8);
          ov[nt] = MFMA16(pf, vf, ov[nt]);
        }
      }
      #pragma unroll
      for (int nt = 0; nt < 2; ++nt)
        #pragma unroll
        for (int r = 0; r < 4; ++r)
          outh[(wave*16 + kg*4 + r)*40 + nt*16 + l15] = f2bf(ov[nt][r]);
    }
    __syncthreads();

    {
      bf16x8 pw[3];
      #pragma unroll
      for (int nt = 0; nt < 3; ++nt)
        pw[nt] = gfrag(proj_bf + (wave*48 + nt*16 + l15)*192 + h*32 + kg*8);
      #pragma unroll
      for (int mt = 0; mt < 4; ++mt){
        bf16x8 af = ldsfrag(outh + (mt*16 + l15)*40 + kg*8);
        #pragma unroll
        for (int nt = 0; nt < 3; ++nt)
          pj[mt][nt] = MFMA16(af, pw[nt], pj[mt][nt]);
      }
    }
    __syncthreads();
  }

  float gv[3], bv2[3];
  #pragma unroll
  for (int nt = 0; nt < 3; ++nt){
    int c = wave*48 + nt*16 + l15;
    gv[nt] = n1g[c]; bv2[nt] = n1b[c];
  }
  #pragma unroll
  for (int mt = 0; mt < 4; ++mt)
    #pragma unroll
    for (int r = 0; r < 4; ++r){
      float s1 = pj[mt][0][r] + pj[mt][1][r] + pj[mt][2][r];
      float s2 = pj[mt][0][r]*pj[mt][0][r] + pj[mt][1][r]*pj[mt][1][r] + pj[mt][2][r]*pj[mt][2][r];
      #pragma unroll
      for (int mk = 1; mk < 16; mk <<= 1){ s1 += __shfl_xor(s1, mk); s2 += __shfl_xor(s2, mk); }
      if (l15 == 0){
        int t = mt*16 + kg*4 + r;
        lnred[t*8 + wave*2]     = s1;
        lnred[t*8 + wave*2 + 1] = s2;
      }
    }
  __syncthreads();
  #pragma unroll
  for (int mt = 0; mt < 4; ++mt)
    #pragma unroll 1
    for (int r = 0; r < 4; ++r){
      int t = mt*16 + kg*4 + r;
      float a1 = lnred[t*8+0] + lnred[t*8+2] + lnred[t*8+4] + lnred[t*8+6];
      float a2 = lnred[t*8+1] + lnred[t*8+3] + lnred[t*8+5] + lnred[t*8+7];
      float mu = a1 * (1.f/192.f);
      float rs = rsqrtf(a2 * (1.f/192.f) - mu*mu + LN_EPS);
      int i = t >> 3, j = t & 7;
      int h0 = ((wh<<3) + i + 4) & 255, w0 = ((ww<<3) + j + 4) & 255;
      size_t base = imgbase + (size_t)(h0*256 + w0)*192;
      #pragma unroll
      for (int nt = 0; nt < 3; ++nt){
        int c = wave*48 + nt*16 + l15;
        x1[base + c] = x[base + c] + (pj[mt][nt][r] - mu)*rs*gv[nt] + bv2[nt];
      }
    }
}

// =====================================================================
// K2: MLP (fc1 + GELU + fc2) + LN2 + residual, IN-PLACE on xio (f32)
// =====================================================================
__global__ __launch_bounds__(256, 3) void k_mlp(
    float* xio, const u16* __restrict__ fc1_bf,
    const float* __restrict__ fc1_b, const u16* __restrict__ fc2_bf,
    const float* __restrict__ fc2_b, const float* __restrict__ n2g,
    const float* __restrict__ n2b)
{
  __shared__ __align__(16) u16 xt[64*200];
  __shared__ __align__(16) u16 hl[64*200];
  __shared__ float lnred[64*8];

  const int tid  = threadIdx.x;
  const int wave = tid >> 6, lane = tid & 63;
  const int kg   = lane >> 4, l15 = lane & 15;
  const size_t t0 = (size_t)blockIdx.x * 64;

  for (int s = tid; s < 64*96; s += 256){
    int t = s / 96, c2 = s - t*96;
    float2 v = LDF2(xio + (t0 + t)*192 + c2*2);
    ST_U32(xt + t*200 + c2*2, pack2(v.x, v.y));
  }
  f32x4 m2[4][3];
  #pragma unroll
  for (int mt = 0; mt < 4; ++mt)
    #pragma unroll
    for (int nt = 0; nt < 3; ++nt){
      float bv = fc2_b[wave*48 + nt*16 + l15];
      m2[mt][nt] = {bv, bv, bv, bv};
    }
  __syncthreads();

  #pragma unroll 1
  for (int c = 0; c < 4; ++c){
    f32x4 a1[4][3];
    #pragma unroll
    for (int mt = 0; mt < 4; ++mt)
      #pragma unroll
      for (int nt = 0; nt < 3; ++nt){
        float bv = fc1_b[c*192 + wave*48 + nt*16 + l15];
        a1[mt][nt] = {bv, bv, bv, bv};
      }
    #pragma unroll 2
    for (int kt = 0; kt < 6; ++kt){
      bf16x8 af[4];
      #pragma unroll
      for (int mt = 0; mt < 4; ++mt)
        af[mt] = ldsfrag(xt + (mt*16 + l15)*200 + kt*32 + kg*8);
      #pragma unroll
      for (int nt = 0; nt < 3; ++nt){
        bf16x8 bfr = gfrag(fc1_bf + (size_t)(c*192 + wave*48 + nt*16 + l15)*192 + kt*32 + kg*8);
        #pragma unroll
        for (int mt = 0; mt < 4; ++mt)
          a1[mt][nt] = MFMA16(af[mt], bfr, a1[mt][nt]);
      }
    }
    #pragma unroll
    for (int mt = 0; mt < 4; ++mt)
      #pragma unroll
      for (int nt = 0; nt < 3; ++nt)
        #pragma unroll
        for (int r = 0; r < 4; ++r)
          hl[(mt*16 + kg*4 + r)*200 + wave*48 + nt*16 + l15] = f2bf(gelu_f(a1[mt][nt][r]));
    __syncthreads();

    #pragma unroll 2
    for (int kt = 0; kt < 6; ++kt){
      bf16x8 af[4];
      #pragma unroll
      for (int mt = 0; mt < 4; ++mt)
        af[mt] = ldsfrag(hl + (mt*16 + l15)*200 + kt*32 + kg*8);
      #pragma unroll
      for (int nt = 0; nt < 3; ++nt){
        bf16x8 bfr = gfrag(fc2_bf + (size_t)(wave*48 + nt*16 + l15)*768 + c*192 + kt*32 + kg*8);
        #pragma unroll
        for (int mt = 0; mt < 4; ++mt)
          m2[mt][nt] = MFMA16(af[mt], bfr, m2[mt][nt]);
      }
    }
    __syncthreads();
  }

  float gv[3], bv2[3];
  #pragma unroll
  for (int nt = 0; nt < 3; ++nt){
    int cc = wave*48 + nt*16 + l15;
    gv[nt] = n2g[cc]; bv2[nt] = n2b[cc];
  }
  #pragma unroll
  for (int mt = 0; mt < 4; ++mt)
    #pragma unroll
    for (int r = 0; r < 4; ++r){
      float s1 = m2[mt][0][r] + m2[mt][1][r] + m2[mt][2][r];
      float s2 = m2[mt][0][r]*m2[mt][0][r] + m2[mt][1][r]*m2[mt][1][r] + m2[mt][2][r]*m2[mt][2][r];
      #pragma unroll
      for (int mk = 1; mk < 16; mk <<= 1){ s1 += __shfl_xor(s1, mk); s2 += __shfl_xor(s2, mk); }
      if (l15 == 0){
        int t = mt*16 + kg*4 + r;
        lnred[t*8 + wave*2]     = s1;
        lnred[t*8 + wave*2 + 1] = s2;
      }
    }
  __syncthreads();
  #pragma unroll
  for (int mt = 0; mt < 4; ++mt)
    #pragma unroll 1
    for (int r = 0; r < 4; ++r){
      int t = mt*16 + kg*4 + r;
      float a1s = lnred[t*8+0] + lnred[t*8+2] + lnred[t*8+4] + lnred[t*8+6];
      float a2s = lnred[t*8+1] + lnred[t*8+3] + lnred[t*8+5] + lnred[t*8+7];
      float mu = a1s * (1.f/192.f);
      float rs = rsqrtf(a2s * (1.f/192.f) - mu*mu + LN_EPS);
      size_t base = (t0 + t)*192;
      #pragma unroll
      for (int nt = 0; nt < 3; ++nt){
        int cc = wave*48 + nt*16 + l15;
        xio[base + cc] = xio[base + cc] + (m2[mt][nt][r] - mu)*rs*gv[nt] + bv2[nt];
      }
    }
}

extern "C" void kernel_launch(void* const* d_in, const int* in_sizes, int n_in,
                              void* d_out, int out_size, void* d_ws, size_t ws_size,
                              hipStream_t stream)
{
  const float* x      = (const float*)d_in[0];
  const float* mask   = (const float*)d_in[1];
  const int*   relidx = (const int*)d_in[2];
  const float* qkv_w  = (const float*)d_in[3];
  const float* qkv_b  = (const float*)d_in[4];
  const float* proj_w = (const float*)d_in[5];
  const float* proj_b = (const float*)d_in[6];
  const float* rpb    = (const float*)d_in[7];
  const float* n1g    = (const float*)d_in[8];
  const float* n1b    = (const float*)d_in[9];
  const float* n2g    = (const float*)d_in[10];
  const float* n2b    = (const float*)d_in[11];
  const float* fc1_w  = (const float*)d_in[12];
  const float* fc1_b  = (const float*)d_in[13];
  const float* fc2_w  = (const float*)d_in[14];
  const float* fc2_b  = (const float*)d_in[15];
  float* xio = (float*)d_out;

  u16* qkv_bf  = (u16*)d_ws;
  u16* proj_bf = qkv_bf + NQKV;
  u16* fc1_bf  = proj_bf + NPRJ;
  u16* fc2_bf  = fc1_bf + NFC;
  float* rpbm  = (float*)(fc2_bf + NFC);
  float* rpbmT = rpbm + 6*4096;
  u16* Qg = (u16*)((char*)d_ws + WS_SPLIT_HDR);
  u16* Kg = Qg + QKV_SLAB;
  u16* VTg = Kg + QKV_SLAB;

  const int split = (ws_size >= WS_SPLIT_NEED) ? 1 : 0;

  k_prep<<<dim3(512), dim3(256), 0, stream>>>(qkv_w, proj_w, fc1_w, fc2_w,
      rpb, relidx, qkv_bf, proj_bf, fc1_bf, fc2_bf, rpbm, rpbmT, split);
  if (split){
    k_qkv<<<dim3(4096), dim3(256), 0, stream>>>(x, qkv_bf, qkv_b, Qg, Kg, VTg);
    k_attn2<<<dim3(4096), dim3(256), 0, stream>>>(x, mask, rpbmT, Qg, Kg, VTg,
        proj_bf, proj_b, n1g, n1b, xio);
  } else {
    k_attn<<<dim3(4096), dim3(256), 0, stream>>>(x, mask, rpbm, qkv_bf, qkv_b,
        proj_bf, proj_b, n1g, n1b, xio);
  }
  k_mlp<<<dim3(4096), dim3(256), 0, stream>>>(xio, fc1_bf, fc1_b, fc2_bf, fc2_b,
      n2g, n2b);
}